// Round 8
// baseline (361.322 us; speedup 1.0000x reference)
//
#include <hip/hip_runtime.h>
#include <hip/hip_bf16.h>

typedef __hip_bfloat16 bf16;
typedef float f32x4 __attribute__((ext_vector_type(4)));
typedef short s16x8 __attribute__((ext_vector_type(8)));

#define NPIX 3136   // 56*56
#define HDIM 56
#define CDIM 256
#define PPIX 3364   // 58*58 padded

static __device__ __forceinline__ float b2f(bf16 v){ return __bfloat162float(v); }
static __device__ __forceinline__ bf16  f2b(float v){ return __float2bfloat16(v); }

// ---- fold region float offsets ----
#define O_KE_S 0
#define O_KE_B 256
#define O_E1_S 512
#define O_E1_B 640
#define O_C1_S 768
#define O_C1_B 1024
#define O_B2_S 1280
#define O_B2_B 1536
#define O_S1_S 1792
#define O_S1_B 1920
#define O_E2B  2048
#define O_GNS  2336   // gnsum[b][grp][2] : 16*32*2 = 1024 floats
#define O_GAP  3360   // raw sums of (y+k) over pixels, scaled by 1/NPIX in attnk
#define O_ATT  7456

// ================= prep: weight converts + BN folds + zeros, one kernel =========
__global__ void prep(
    const float* __restrict__ kew, const float* __restrict__ e1w,
    const float* __restrict__ e2w, const float* __restrict__ c1w,
    const float* keg, const float* keb, const float* kem, const float* kev,
    const float* e1g, const float* e1b, const float* e1m, const float* e1v,
    const float* e2b,
    const float* c1g, const float* c1b, const float* c1m, const float* c1v,
    const float* b2g, const float* b2b, const float* b2m, const float* b2v,
    const float* s1g, const float* s1bb, const float* s1m, const float* s1v,
    bf16* kewT, bf16* e1wb, bf16* e2wb, bf16* c1wb, float* o)
{
    int bid = blockIdx.x, t = threadIdx.x;
    if (bid < 576) {                       // kewT: (256,64,3,3) -> [g][tap][co_l][ci]
        int i = bid * 256 + t;
        int ci = i & 63, co_l = (i >> 6) & 63;
        int gt = i >> 12;
        int tap = gt % 9, g = gt / 9;
        int co = g * 64 + co_l;
        kewT[i] = f2b(kew[(co * 64 + ci) * 9 + tap]);
    } else if (bid < 832) {
        int i = (bid - 576) * 256 + t; e1wb[i] = f2b(e1w[i]);
    } else if (bid < 976) {
        int i = (bid - 832) * 256 + t; e2wb[i] = f2b(e2w[i]);
    } else if (bid < 1232) {
        int i = (bid - 976) * 256 + t; c1wb[i] = f2b(c1w[i]);
    } else if (bid == 1232) {
        const float eps = 1e-5f;
        {
            float s = keg[t] * rsqrtf(kev[t] + eps);
            o[O_KE_S + t] = s; o[O_KE_B + t] = keb[t] - kem[t] * s;
            s = c1g[t] * rsqrtf(c1v[t] + eps);
            o[O_C1_S + t] = s; o[O_C1_B + t] = c1b[t] - c1m[t] * s;
            s = b2g[t] * rsqrtf(b2v[t] + eps);
            o[O_B2_S + t] = s; o[O_B2_B + t] = b2b[t] - b2m[t] * s;
        }
        if (t < 128) {
            float s = e1g[t] * rsqrtf(e1v[t] + eps);
            o[O_E1_S + t] = s; o[O_E1_B + t] = e1b[t] - e1m[t] * s;
            s = s1g[t] * rsqrtf(s1v[t] + eps);
            o[O_S1_S + t] = s; o[O_S1_B + t] = s1bb[t] - s1m[t] * s;
        }
        for (int i = t; i < 288; i += 256) o[O_E2B + i] = e2b[i];
    } else {                                // zeros: gnsum (1024) + gap (4096)
        int j = (bid - 1233) * 256 + t;
        if (j < 1024) o[O_GNS + j] = 0.f;
        else          o[O_GAP + j - 1024] = 0.f;
    }
}

// ================= x: fp32 NCHW -> bf16 NHWC (58x58 zero-padded) ===============
// Also zeroes the xq border (xq is written padded by gemm_pair later).
__global__ __launch_bounds__(256) void cvt_x(const float* __restrict__ x,
                                             bf16* __restrict__ xh, bf16* __restrict__ xq)
{
    int b = blockIdx.y;
    int p0 = blockIdx.x * 64;
    __shared__ bf16 T[64][264];
    int t = threadIdx.x;

    // zero the pad border once per image (block x==0): 228 positions x 256 ch
    if (blockIdx.x == 0) {
        float4 z = {0.f, 0.f, 0.f, 0.f};
        for (int s = t; s < 7296; s += 256) {
            int pi = s >> 5, cc = s & 31;
            int pos;
            if (pi < 58)       pos = pi;                     // top row
            else if (pi < 116) pos = 57 * 58 + (pi - 58);    // bottom row
            else if (pi < 172) pos = (pi - 115) * 58;        // left col rows 1..56
            else               pos = (pi - 171) * 58 + 57;   // right col rows 1..56
            *(float4*)(xh + ((long)b * PPIX + pos) * 256 + cc * 8) = z;
            *(float4*)(xq + ((long)b * PPIX + pos) * 256 + cc * 8) = z;
        }
    }

    for (int it = 0; it < 16; it++) {
        int slot = t + it * 256;
        int c = slot >> 4, ch4 = slot & 15;
        float4 v = *(const float4*)(x + ((long)b * CDIM + c) * NPIX + p0 + ch4 * 4);
        T[ch4 * 4 + 0][c] = f2b(v.x);
        T[ch4 * 4 + 1][c] = f2b(v.y);
        T[ch4 * 4 + 2][c] = f2b(v.z);
        T[ch4 * 4 + 3][c] = f2b(v.w);
    }
    __syncthreads();
    for (int it = 0; it < 8; it++) {
        int slot = t + it * 256;
        int p = slot >> 5, cc = slot & 31;
        int pl = p0 + p;
        int h = pl / HDIM, w = pl - h * HDIM;
        *(float4*)(xh + ((long)b * PPIX + (h + 1) * 58 + (w + 1)) * 256 + cc * 8) = *(const float4*)&T[p][cc * 8];
    }
}

// ================= grouped 3x3 conv: 2-row tile, swizzled LDS, MFMA ============
// grid (28, 4, 16) = (2-row tile, group, batch), block 256 (4 waves, co-split)
// Epilogue also accumulates the k-part of the GAP (raw sum over pixels).
__global__ __launch_bounds__(256, 4) void gconv_mfma(
    const bf16* __restrict__ xp, const bf16* __restrict__ wT,
    const float* __restrict__ scale, const float* __restrict__ bias,
    bf16* __restrict__ kh, float* __restrict__ gap)
{
    int b = blockIdx.z, g = blockIdx.y;
    int h0 = blockIdx.x * 2;               // padded halo rows h0..h0+3
    __shared__ bf16 As[232 * 64];          // 29,696 B; epilogue T aliases
    int t = threadIdx.x;
    int wv = t >> 6, lane = t & 63, q = lane >> 4, ln = lane & 15;

    // ---- stage halo: 232 pos x 8 chunks (16B), chunk XOR-swizzled by pos&7 ----
    #pragma unroll
    for (int i = 0; i < 8; i++) {
        int slot = t + i * 256;
        if (slot < 1856) {
            int pos = slot >> 3, chunkL = slot & 7;
            int ri = pos / 58, ci = pos - ri * 58;
            int chunkg = chunkL ^ (pos & 7);
            float4 v = *(const float4*)(xp + (((long)b * PPIX + (h0 + ri) * 58 + ci) * 256 + g * 64 + chunkg * 8));
            *(float4*)&As[pos * 64 + chunkL * 8] = v;
        }
    }

    // per-lane pixel positions for the 7 px-subtiles (112 px = 2 image rows)
    int posb[7];
    #pragma unroll
    for (int pt = 0; pt < 7; pt++) {
        int p = pt * 16 + ln;              // 0..111
        int prow = (p >= 56) ? 1 : 0;
        int pcol = p - prow * 56;
        posb[pt] = prow * 58 + pcol + 1;
    }
    const bf16* wbase = wT + ((long)(g * 9) * 64 + wv * 16 + ln) * 64;

    __syncthreads();

    f32x4 acc[7] = {};
    #pragma unroll
    for (int tap = 0; tap < 9; tap++) {
        const int dr = tap / 3;
        const int dc = tap % 3 - 1;
        const bf16* wq = wbase + tap * 64 * 64;
        s16x8 B0 = *(const s16x8*)(wq + q * 8);
        s16x8 B1 = *(const s16x8*)(wq + 32 + q * 8);
        #pragma unroll
        for (int pt = 0; pt < 7; pt++) {
            int pos = posb[pt] + dr * 58 + dc;
            int off0 = pos * 64 + ((q ^ (pos & 7)) * 8);
            s16x8 a0 = *(const s16x8*)&As[off0];
            s16x8 a1 = *(const s16x8*)&As[off0 ^ 32];
            acc[pt] = __builtin_amdgcn_mfma_f32_16x16x32_bf16(a0, B0, acc[pt], 0, 0, 0);
            acc[pt] = __builtin_amdgcn_mfma_f32_16x16x32_bf16(a1, B1, acc[pt], 0, 0, 0);
        }
    }

    // ---- epilogue: BN+ReLU, transpose via LDS (aliases As), coalesced store ----
    __syncthreads();
    bf16* T = As;                          // 112 x 72 = 8064 elem < 14848
    int co = g * 64 + wv * 16 + ln;
    float sc = scale[co], bi = bias[co];
    #pragma unroll
    for (int pt = 0; pt < 7; pt++)
        #pragma unroll
        for (int r = 0; r < 4; r++)
            T[(pt * 16 + q * 4 + r) * 72 + wv * 16 + ln] = f2b(fmaxf(acc[pt][r] * sc + bi, 0.f));
    __syncthreads();
    int pimg0 = blockIdx.x * 112;
    #pragma unroll
    for (int i = 0; i < 4; i++) {
        int slot = t + i * 256;
        if (slot < 896) {
            int row = slot >> 3, cc = slot & 7;
            *(float4*)(kh + ((long)b * NPIX + pimg0 + row) * CDIM + g * 64 + cc * 8) = *(const float4*)&T[row * 72 + cc * 8];
        }
    }
    // ---- fused k-GAP partial: sum T over 112 rows per channel, 1 atomic/thread
    {
        int co_l = t & 63, rb = t >> 6;
        float s = 0.f;
        #pragma unroll
        for (int r = 0; r < 28; r++) s += b2f(T[(rb * 28 + r) * 72 + co_l]);
        atomicAdd(&gap[b * 256 + g * 64 + co_l], s);
    }
}

// ================= fused e1+c1 1x1-conv GEMM (independent, one launch) =========
// grid (49, 3, 16): by==0 -> e1 (K=512, M=128, ReLU, unpadded out);
// by in {1,2} -> c1 (K=256, M=256, no ReLU, PADDED out).
__global__ __launch_bounds__(256) void gemm_pair(
    const bf16* __restrict__ e1w, const bf16* __restrict__ c1w,
    const bf16* __restrict__ X0, const bf16* __restrict__ X1,
    const float* __restrict__ fold,
    bf16* __restrict__ Ye1, bf16* __restrict__ Yc1)
{
    int b = blockIdx.z;
    int p0 = blockIdx.x * 64;
    int by = blockIdx.y;
    const bf16* Wt; int K, M, m0; const float *scp, *bip; bf16* Y; bool relu;
    if (by == 0) { Wt = e1w; K = 512; M = 128; m0 = 0;
                   scp = fold + O_E1_S; bip = fold + O_E1_B; Y = Ye1; relu = true; }
    else         { Wt = c1w; K = 256; M = 256; m0 = (by - 1) * 128;
                   scp = fold + O_C1_S; bip = fold + O_C1_B; Y = Yc1; relu = false; }
    const int C0 = 256;

    __shared__ bf16 SH[64 * 72 + 128 * 72];   // As | Bs ; epilogue T aliases
    bf16* As = SH;
    bf16* Bs = SH + 64 * 72;
    int t = threadIdx.x;
    int wv = t >> 6, lane = t & 63, q = lane >> 4, ln = lane & 15;

    f32x4 acc[4][2] = {};
    for (int k0 = 0; k0 < K; k0 += 64) {
        __syncthreads();
        #pragma unroll
        for (int i = 0; i < 2; i++) {
            int slot = t + i * 256;
            int chunk = slot & 7, row = slot >> 3;
            int ch = k0 + chunk * 8;
            const bf16* src;
            if (ch < C0) {
                long pp = p0 + row;
                long pidx = (long)b * PPIX + pp + 2 * (pp / HDIM) + 59;
                src = X0 + pidx * C0 + ch;
            } else {
                src = X1 + ((long)b * NPIX + p0 + row) * 256 + (ch - C0);
            }
            *(float4*)&As[row * 72 + chunk * 8] = *(const float4*)src;
        }
        #pragma unroll
        for (int i = 0; i < 4; i++) {
            int slot = t + i * 256;
            int chunk = slot & 7, row = slot >> 3;
            *(float4*)&Bs[row * 72 + chunk * 8] = *(const float4*)(Wt + (long)(m0 + row) * K + k0 + chunk * 8);
        }
        __syncthreads();
        #pragma unroll
        for (int kk = 0; kk < 2; kk++) {
            s16x8 a[4];
            #pragma unroll
            for (int pt = 0; pt < 4; pt++)
                a[pt] = *(const s16x8*)&As[(pt * 16 + ln) * 72 + kk * 32 + q * 8];
            #pragma unroll
            for (int mi = 0; mi < 2; mi++) {
                s16x8 bb = *(const s16x8*)&Bs[(wv * 32 + mi * 16 + ln) * 72 + kk * 32 + q * 8];
                #pragma unroll
                for (int pt = 0; pt < 4; pt++)
                    acc[pt][mi] = __builtin_amdgcn_mfma_f32_16x16x32_bf16(a[pt], bb, acc[pt][mi], 0, 0, 0);
            }
        }
    }

    __syncthreads();
    bf16* T = SH;                     // 64 x 144
    #pragma unroll
    for (int mi = 0; mi < 2; mi++) {
        int m = m0 + wv * 32 + mi * 16 + ln;
        float sc = scp[m], bi = bip[m];
        #pragma unroll
        for (int pt = 0; pt < 4; pt++) {
            #pragma unroll
            for (int r = 0; r < 4; r++) {
                float v = acc[pt][mi][r] * sc + bi;
                if (relu) v = fmaxf(v, 0.f);
                T[(pt * 16 + q * 4 + r) * 144 + wv * 32 + mi * 16 + ln] = f2b(v);
            }
        }
    }
    __syncthreads();
    // store: 64 rows x 16 chunks of 16B (128 m-columns per tile)
    #pragma unroll
    for (int i = 0; i < 4; i++) {
        int slot = t + i * 256;
        int row = slot >> 4, chunk = slot & 15;
        long pp = p0 + row;
        long pidx = (by == 0) ? ((long)b * NPIX + pp)
                              : ((long)b * PPIX + pp + 2 * (pp / HDIM) + 59);
        *(float4*)(Y + pidx * M + m0 + chunk * 8) = *(const float4*)&T[row * 144 + chunk * 8];
    }
}

// ================= 1x1 conv GEMM (e2): +bias + fused GN partial sums ===========
// grid (49, 3, 16), block 256 (4 waves)
__global__ __launch_bounds__(256) void mfma_gemm_e2(
    const bf16* __restrict__ Wt, const bf16* __restrict__ X0,
    const float* __restrict__ bias,
    bf16* __restrict__ Y, float* __restrict__ gnsum)
{
    const int K = 128, M = 288;
    int b = blockIdx.z;
    int p0 = blockIdx.x * 64;
    int m0 = blockIdx.y * 128;
    __shared__ bf16 SH[64 * 72 + 128 * 72];
    bf16* As = SH;
    bf16* Bs = SH + 64 * 72;
    __shared__ float gs[64];
    int t = threadIdx.x;
    int wv = t >> 6, lane = t & 63, q = lane >> 4, ln = lane & 15;
    if (t < 64) gs[t] = 0.f;

    f32x4 acc[4][2] = {};
    for (int k0 = 0; k0 < K; k0 += 64) {
        __syncthreads();
        #pragma unroll
        for (int i = 0; i < 2; i++) {
            int slot = t + i * 256;
            int chunk = slot & 7, row = slot >> 3;
            int ch = k0 + chunk * 8;
            *(float4*)&As[row * 72 + chunk * 8] = *(const float4*)(X0 + ((long)b * NPIX + p0 + row) * K + ch);
        }
        #pragma unroll
        for (int i = 0; i < 4; i++) {
            int slot = t + i * 256;
            int chunk = slot & 7, row = slot >> 3;
            int m = m0 + row;
            float4 v = {0.f, 0.f, 0.f, 0.f};
            if (m < M) v = *(const float4*)(Wt + (long)m * K + k0 + chunk * 8);
            *(float4*)&Bs[row * 72 + chunk * 8] = v;
        }
        __syncthreads();
        #pragma unroll
        for (int kk = 0; kk < 2; kk++) {
            s16x8 a[4];
            #pragma unroll
            for (int pt = 0; pt < 4; pt++)
                a[pt] = *(const s16x8*)&As[(pt * 16 + ln) * 72 + kk * 32 + q * 8];
            #pragma unroll
            for (int mi = 0; mi < 2; mi++) {
                s16x8 bb = *(const s16x8*)&Bs[(wv * 32 + mi * 16 + ln) * 72 + kk * 32 + q * 8];
                #pragma unroll
                for (int pt = 0; pt < 4; pt++)
                    acc[pt][mi] = __builtin_amdgcn_mfma_f32_16x16x32_bf16(a[pt], bb, acc[pt][mi], 0, 0, 0);
            }
        }
    }

    __syncthreads();
    bf16* T = SH;
    #pragma unroll
    for (int mi = 0; mi < 2; mi++) {
        int m = m0 + wv * 32 + mi * 16 + ln;
        int mc = (m > M - 1) ? (M - 1) : m;
        float bi = bias[mc];
        float ps = 0.f, pq = 0.f;
        #pragma unroll
        for (int pt = 0; pt < 4; pt++) {
            #pragma unroll
            for (int r = 0; r < 4; r++) {
                float v = acc[pt][mi][r] + bi;
                ps += v; pq += v * v;
                T[(pt * 16 + q * 4 + r) * 144 + wv * 32 + mi * 16 + ln] = f2b(v);
            }
        }
        if (m < M) {
            int grp = m / 9;
            atomicAdd(&gs[grp * 2], ps);
            atomicAdd(&gs[grp * 2 + 1], pq);
        }
    }
    __syncthreads();
    #pragma unroll
    for (int i = 0; i < 4; i++) {
        int slot = t + i * 256;
        int chunk = slot & 15, row = slot >> 4;
        int m = m0 + chunk * 8;
        if (m + 8 <= M)
            *(float4*)(Y + ((long)b * NPIX + p0 + row) * M + m) = *(const float4*)&T[row * 144 + chunk * 8];
    }
    if (t < 64) atomicAdd(&gnsum[b * 64 + t], gs[t]);
}

// ================= dynamic local conv + inline GN + BN(b2) + swish + y-GAP =====
// block = 8 consecutive pixels x 32 groups. xq neighborhood (3 rows x 10 cols x
// 256 ch) is staged cooperatively into LDS (960 coalesced float4 loads, issued
// in parallel) -> one latency exposure instead of 9 serial per-thread trips.
__global__ __launch_bounds__(256) void dynconv(
    const bf16* __restrict__ xq, const bf16* __restrict__ wemb,
    const float* __restrict__ gnsum,
    const float* __restrict__ gng, const float* __restrict__ gnb,
    const float* __restrict__ b2s, const float* __restrict__ b2b,
    bf16* __restrict__ y, float* __restrict__ gap)
{
    int t = threadIdx.x;
    int grp = t & 31, pl = t >> 5;
    int bid = blockIdx.x;                  // 16 b x 392 tiles
    int b = bid / 392;
    int p0 = (bid - b * 392) * 8;
    int p = p0 + pl;
    int h = p0 / HDIM, w0 = p0 - h * HDIM; // all 8 px in image row h (8 | 56)

    __shared__ bf16 TS[30 * 264];          // 3 rows x 10 cols x 256ch (+8 pad)
    __shared__ bf16 WE[2304];              // 8 px x 288 wemb slab
    __shared__ float SA[288], SC[288];

    // ---- stage xq tile: 30 positions x 32 chunks of 16B, fully coalesced ----
    // padded position of image (h+r-1, w0+c-1) = (h+r)*58 + (w0+c), r<3, c<10
    long tbase = (long)b * PPIX * 256;
    #pragma unroll
    for (int i = 0; i < 4; i++) {
        int slot = t + i * 256;
        if (slot < 960) {
            int pos = slot >> 5, chunk = slot & 31;
            int r = pos / 10, c = pos - r * 10;
            float4 v = *(const float4*)(xq + tbase + ((long)(h + r) * 58 + (w0 + c)) * 256 + chunk * 8);
            *(float4*)&TS[pos * 264 + chunk * 8] = v;
        }
    }
    // ---- stage wemb slab ----
    {
        const bf16* src = wemb + (long)(b * NPIX + p0) * 288;
        #pragma unroll
        for (int i = 0; i < 2; i++) {
            int s = t + i * 256;
            if (s < 288) *(float4*)&WE[s * 8] = *(const float4*)(src + s * 8);
        }
    }
    // ---- GN fold per (grp, tap) ----
    for (int s = t; s < 288; s += 256) {
        int g2 = s / 9;
        float S = gnsum[b * 64 + g2 * 2], Q = gnsum[b * 64 + g2 * 2 + 1];
        float mu = S * (1.f / 28224.f);
        float var = Q * (1.f / 28224.f) - mu * mu;
        float rs = rsqrtf(fmaxf(var, 0.f) + 1e-5f);
        float a = rs * gng[s];
        SA[s] = a;
        SC[s] = gnb[s] - mu * a;
    }
    __syncthreads();

    float acc[8] = {};
    #pragma unroll
    for (int i = 0; i < 3; i++) {
        #pragma unroll
        for (int j = 0; j < 3; j++) {
            int tp = i * 3 + j;
            int wi = grp * 9 + tp;
            float wt = b2f(WE[pl * 288 + wi]) * SA[wi] + SC[wi];
            s16x8 xv = *(const s16x8*)&TS[(i * 10 + pl + j) * 264 + grp * 8];
            const bf16* xb = (const bf16*)&xv;
            #pragma unroll
            for (int e = 0; e < 8; e++) acc[e] += b2f(xb[e]) * wt;
        }
    }

    bf16 outv[8];
    float sv[8];
    #pragma unroll
    for (int i = 0; i < 8; i++) {
        int c = grp * 8 + i;
        float v = acc[i] * b2s[c] + b2b[c];
        float sw = v / (1.f + __expf(-v));
        sv[i] = sw;
        outv[i] = f2b(sw);
    }
    *(float4*)(y + ((long)b * NPIX + p) * CDIM + grp * 8) = *(const float4*)outv;

    // ---- fused y-GAP: R aliases TS (all TS reads done; barrier first) ----
    __syncthreads();
    float* R = (float*)TS;                 // 8 x 256 floats = 8192 B < 15840 B
    #pragma unroll
    for (int i = 0; i < 8; i++) R[pl * 256 + grp * 8 + i] = sv[i];
    __syncthreads();
    float s = 0.f;
    #pragma unroll
    for (int j = 0; j < 8; j++) s += R[j * 256 + t];
    atomicAdd(&gap[b * 256 + t], s);
}

// ================= split attention ============================================
__global__ void attnk(const float* __restrict__ gap,
                      const float* __restrict__ s1w, const float* __restrict__ s1b,
                      const float* __restrict__ s1s, const float* __restrict__ s1bi,
                      const float* __restrict__ s2w, const float* __restrict__ s2b,
                      float* __restrict__ att)
{
    int b = blockIdx.x, t = threadIdx.x;   // 128 threads
    __shared__ float g[256], a1[128];
    for (int i = t; i < 256; i += 128) g[i] = gap[b * 256 + i] * (1.f / NPIX);
    __syncthreads();
    float s = 0.f;
    for (int ci = 0; ci < 256; ci++) s += s1w[t * 256 + ci] * g[ci];
    s += s1b[t];
    s = s * s1s[t] + s1bi[t];
    a1[t] = fmaxf(s, 0.f);
    __syncthreads();
    for (int c = t; c < 256; c += 128) {
        float v0 = s2b[2 * c], v1 = s2b[2 * c + 1];
        for (int ci = 0; ci < 128; ci++) {
            float av = a1[ci];
            v0 += s2w[(2 * c) * 128 + ci] * av;
            v1 += s2w[(2 * c + 1) * 128 + ci] * av;
        }
        float m = fmaxf(v0, v1);
        float e0 = __expf(v0 - m), e1 = __expf(v1 - m);
        float inv = 1.f / (e0 + e1);
        att[(b * 256 + c) * 2 + 0] = e0 * inv;
        att[(b * 256 + c) * 2 + 1] = e1 * inv;
    }
}

// ================= final: combine + NHWC->NCHW fp32 out =======================
__global__ __launch_bounds__(256) void finalk(
    const bf16* __restrict__ y, const bf16* __restrict__ k,
    const float* __restrict__ att, float* __restrict__ out)
{
    int b = blockIdx.z, c0 = blockIdx.y * 64, p0 = blockIdx.x * 64;
    __shared__ bf16 Ys[64][72], Ks[64][72];
    int t = threadIdx.x;
    #pragma unroll
    for (int i = 0; i < 2; i++) {
        int slot = t + i * 256;
        int row = slot >> 3, cc = slot & 7;
        long off = ((long)b * NPIX + p0 + row) * CDIM + c0 + cc * 8;
        *(float4*)&Ys[row][cc * 8] = *(const float4*)(y + off);
        *(float4*)&Ks[row][cc * 8] = *(const float4*)(k + off);
    }
    __syncthreads();
    int c_l = t >> 2, pc = t & 3;
    int c = c0 + c_l;
    float a0 = att[(b * 256 + c) * 2], a1 = att[(b * 256 + c) * 2 + 1];
    float4 o[4];
    float* of = (float*)o;
    #pragma unroll
    for (int j = 0; j < 16; j++) {
        int p = pc * 16 + j;
        of[j] = b2f(Ys[p][c_l]) * a0 + b2f(Ks[p][c_l]) * a1;
    }
    float* dst = out + ((long)b * CDIM + c) * NPIX + p0 + pc * 16;
    #pragma unroll
    for (int j = 0; j < 4; j++) ((float4*)dst)[j] = o[j];
}

extern "C" void kernel_launch(void* const* d_in, const int* in_sizes, int n_in,
                              void* d_out, int out_size, void* d_ws, size_t ws_size,
                              hipStream_t stream)
{
    const float* x    = (const float*)d_in[0];
    const float* ke_w = (const float*)d_in[1];
    const float* ke_g = (const float*)d_in[2];
    const float* ke_b = (const float*)d_in[3];
    const float* ke_m = (const float*)d_in[4];
    const float* ke_v = (const float*)d_in[5];
    const float* e1_w = (const float*)d_in[6];
    const float* e1_g = (const float*)d_in[7];
    const float* e1_b = (const float*)d_in[8];
    const float* e1_m = (const float*)d_in[9];
    const float* e1_v = (const float*)d_in[10];
    const float* e2_w = (const float*)d_in[11];
    const float* e2_b = (const float*)d_in[12];
    const float* gng  = (const float*)d_in[13];
    const float* gnb  = (const float*)d_in[14];
    const float* c1_w = (const float*)d_in[15];
    const float* c1_g = (const float*)d_in[16];
    const float* c1_b = (const float*)d_in[17];
    const float* c1_m = (const float*)d_in[18];
    const float* c1_v = (const float*)d_in[19];
    const float* b2_g = (const float*)d_in[20];
    const float* b2_b = (const float*)d_in[21];
    const float* b2_m = (const float*)d_in[22];
    const float* b2_v = (const float*)d_in[23];
    const float* s1_w = (const float*)d_in[24];
    const float* s1_b = (const float*)d_in[25];
    const float* s1_g = (const float*)d_in[26];
    const float* s1_bb= (const float*)d_in[27];
    const float* s1_m = (const float*)d_in[28];
    const float* s1_v = (const float*)d_in[29];
    const float* s2_w = (const float*)d_in[30];
    const float* s2_b = (const float*)d_in[31];

    float* fold = (float*)d_ws;
    bf16* wsb   = (bf16*)((char*)d_ws + 65536);
    bf16* xh   = wsb;                     // padded: 16*3364*256 = 13,778,944
    bf16* kh   = xh + 13778944L;          // 12,845,056
    bf16* wemb = kh + 12845056L;          // 14,450,688
    bf16* w1   = wemb + 14450688L;        // 6,422,528 (e1 out)
    bf16* kewT = w1 + 6422528L;           // 147,456
    bf16* e1wb = kewT + 147456L;          // 65,536
    bf16* e2wb = e1wb + 65536L;           // 36,864
    bf16* c1wb = e2wb + 36864L;           // 65,536
    bf16* xq   = c1wb + 65536L;           // padded: 13,778,944
    bf16* yb   = xh;                      // alias (xh dead after gemm_pair; unpadded)

    prep<<<dim3(1253), dim3(256), 0, stream>>>(
        ke_w, e1_w, e2_w, c1_w,
        ke_g, ke_b, ke_m, ke_v, e1_g, e1_b, e1_m, e1_v, e2_b,
        c1_g, c1_b, c1_m, c1_v, b2_g, b2_b, b2_m, b2_v,
        s1_g, s1_bb, s1_m, s1_v,
        kewT, e1wb, e2wb, c1wb, fold);

    cvt_x<<<dim3(49, 16), dim3(256), 0, stream>>>(x, xh, xq);

    gconv_mfma<<<dim3(28, 4, 16), dim3(256), 0, stream>>>(
        xh, kewT, fold + O_KE_S, fold + O_KE_B, kh, fold + O_GAP);

    gemm_pair<<<dim3(49, 3, 16), dim3(256), 0, stream>>>(
        e1wb, c1wb, xh, kh, fold, w1, xq);

    mfma_gemm_e2<<<dim3(49, 3, 16), dim3(256), 0, stream>>>(
        e2wb, w1, fold + O_E2B, wemb, fold + O_GNS);

    dynconv<<<dim3(6272), dim3(256), 0, stream>>>(
        xq, wemb, fold + O_GNS, gng, gnb,
        fold + O_B2_S, fold + O_B2_B, yb, fold + O_GAP);

    attnk<<<dim3(16), dim3(128), 0, stream>>>(
        fold + O_GAP, s1_w, s1_b, fold + O_S1_S, fold + O_S1_B, s2_w, s2_b, fold + O_ATT);

    finalk<<<dim3(49, 4, 16), dim3(256), 0, stream>>>(yb, kh, fold + O_ATT, (float*)d_out);
}

// Round 9
// 352.517 us; speedup vs baseline: 1.0250x; 1.0250x over previous
//
#include <hip/hip_runtime.h>
#include <hip/hip_bf16.h>

typedef __hip_bfloat16 bf16;
typedef float f32x4 __attribute__((ext_vector_type(4)));
typedef short s16x8 __attribute__((ext_vector_type(8)));

#define NPIX 3136   // 56*56
#define HDIM 56
#define CDIM 256
#define PPIX 3364   // 58*58 padded

static __device__ __forceinline__ float b2f(bf16 v){ return __bfloat162float(v); }
static __device__ __forceinline__ bf16  f2b(float v){ return __float2bfloat16(v); }

// ---- fold region float offsets ----
#define O_KE_S 0
#define O_KE_B 256
#define O_E1_S 512
#define O_E1_B 640
#define O_C1_S 768
#define O_C1_B 1024
#define O_B2_S 1280
#define O_B2_B 1536
#define O_S1_S 1792
#define O_S1_B 1920
#define O_E2B  2048
#define O_GNS  2336   // gnsum[b][grp][2] : 16*32*2 = 1024 floats
#define O_GAP  3360   // raw sums of (y+k) over pixels, scaled by 1/NPIX in attnk
#define O_ATT  7456

// ================= prep: weight converts + BN folds + zeros + pad borders ======
__global__ void prep(
    const float* __restrict__ kew, const float* __restrict__ e1w,
    const float* __restrict__ e2w, const float* __restrict__ c1w,
    const float* keg, const float* keb, const float* kem, const float* kev,
    const float* e1g, const float* e1b, const float* e1m, const float* e1v,
    const float* e2b,
    const float* c1g, const float* c1b, const float* c1m, const float* c1v,
    const float* b2g, const float* b2b, const float* b2m, const float* b2v,
    const float* s1g, const float* s1bb, const float* s1m, const float* s1v,
    bf16* kewT, bf16* e1wb, bf16* e2wb, bf16* c1wb, float* o,
    bf16* xh, bf16* xq)
{
    int bid = blockIdx.x, t = threadIdx.x;
    if (bid < 576) {                       // kewT: (256,64,3,3) -> [g][tap][co_l][ci]
        int i = bid * 256 + t;
        int ci = i & 63, co_l = (i >> 6) & 63;
        int gt = i >> 12;
        int tap = gt % 9, g = gt / 9;
        int co = g * 64 + co_l;
        kewT[i] = f2b(kew[(co * 64 + ci) * 9 + tap]);
    } else if (bid < 832) {
        int i = (bid - 576) * 256 + t; e1wb[i] = f2b(e1w[i]);
    } else if (bid < 976) {
        int i = (bid - 832) * 256 + t; e2wb[i] = f2b(e2w[i]);
    } else if (bid < 1232) {
        int i = (bid - 976) * 256 + t; c1wb[i] = f2b(c1w[i]);
    } else if (bid == 1232) {
        const float eps = 1e-5f;
        {
            float s = keg[t] * rsqrtf(kev[t] + eps);
            o[O_KE_S + t] = s; o[O_KE_B + t] = keb[t] - kem[t] * s;
            s = c1g[t] * rsqrtf(c1v[t] + eps);
            o[O_C1_S + t] = s; o[O_C1_B + t] = c1b[t] - c1m[t] * s;
            s = b2g[t] * rsqrtf(b2v[t] + eps);
            o[O_B2_S + t] = s; o[O_B2_B + t] = b2b[t] - b2m[t] * s;
        }
        if (t < 128) {
            float s = e1g[t] * rsqrtf(e1v[t] + eps);
            o[O_E1_S + t] = s; o[O_E1_B + t] = e1b[t] - e1m[t] * s;
            s = s1g[t] * rsqrtf(s1v[t] + eps);
            o[O_S1_S + t] = s; o[O_S1_B + t] = s1bb[t] - s1m[t] * s;
        }
        for (int i = t; i < 288; i += 256) o[O_E2B + i] = e2b[i];
    } else if (bid < 1253) {                // zeros: gnsum (1024) + gap (4096)
        int j = (bid - 1233) * 256 + t;
        if (j < 1024) o[O_GNS + j] = 0.f;
        else if (j < 5120) o[O_GAP + j - 1024] = 0.f;
    } else {                                // pad borders of xh and xq (zero)
        int j = (bid - 1253) * 256 + t;     // 0 .. 233471 = 2*16*7296
        bf16* arr = (j >= 116736) ? xq : xh;
        int r = j % 116736;
        int img = r / 7296;
        int s = r % 7296;
        int pi = s >> 5, cc = s & 31;
        int pos;
        if (pi < 58)       pos = pi;                     // top row
        else if (pi < 116) pos = 57 * 58 + (pi - 58);    // bottom row
        else if (pi < 172) pos = (pi - 115) * 58;        // left col rows 1..56
        else               pos = (pi - 171) * 58 + 57;   // right col rows 1..56
        float4 z = {0.f, 0.f, 0.f, 0.f};
        *(float4*)(arr + ((long)img * PPIX + pos) * 256 + cc * 8) = z;
    }
}

// ================= x: fp32 NCHW -> bf16 NHWC (58x58 zero-padded interior) ======
// grid (49, 4, 16): 64px x 64ch tile per block -> 3136 blocks (12/CU).
__global__ __launch_bounds__(256) void cvt_x(const float* __restrict__ x, bf16* __restrict__ xh)
{
    int b = blockIdx.z;
    int c0 = blockIdx.y * 64;
    int p0 = blockIdx.x * 64;
    __shared__ bf16 T[64][72];
    int t = threadIdx.x;
    #pragma unroll
    for (int it = 0; it < 4; it++) {
        int slot = t + it * 256;           // 0..1023
        int cl = slot >> 4, ch4 = slot & 15;
        float4 v = *(const float4*)(x + ((long)b * CDIM + c0 + cl) * NPIX + p0 + ch4 * 4);
        T[ch4 * 4 + 0][cl] = f2b(v.x);
        T[ch4 * 4 + 1][cl] = f2b(v.y);
        T[ch4 * 4 + 2][cl] = f2b(v.z);
        T[ch4 * 4 + 3][cl] = f2b(v.w);
    }
    __syncthreads();
    #pragma unroll
    for (int it = 0; it < 2; it++) {
        int slot = t + it * 256;           // 0..511
        int p = slot >> 3, cc = slot & 7;
        int pl = p0 + p;
        int h = pl / HDIM, w = pl - h * HDIM;
        *(float4*)(xh + ((long)b * PPIX + (h + 1) * 58 + (w + 1)) * 256 + c0 + cc * 8) = *(const float4*)&T[p][cc * 8];
    }
}

// ================= grouped 3x3 conv: 2-row tile, swizzled LDS, MFMA ============
// grid (28, 4, 16) = (2-row tile, group, batch), block 256 (4 waves, co-split)
// Epilogue also accumulates the k-part of the GAP (raw sum over pixels).
__global__ __launch_bounds__(256, 4) void gconv_mfma(
    const bf16* __restrict__ xp, const bf16* __restrict__ wT,
    const float* __restrict__ scale, const float* __restrict__ bias,
    bf16* __restrict__ kh, float* __restrict__ gap)
{
    int b = blockIdx.z, g = blockIdx.y;
    int h0 = blockIdx.x * 2;               // padded halo rows h0..h0+3
    __shared__ bf16 As[232 * 64];          // 29,696 B; epilogue T aliases
    int t = threadIdx.x;
    int wv = t >> 6, lane = t & 63, q = lane >> 4, ln = lane & 15;

    // ---- stage halo: 232 pos x 8 chunks (16B), chunk XOR-swizzled by pos&7 ----
    #pragma unroll
    for (int i = 0; i < 8; i++) {
        int slot = t + i * 256;
        if (slot < 1856) {
            int pos = slot >> 3, chunkL = slot & 7;
            int ri = pos / 58, ci = pos - ri * 58;
            int chunkg = chunkL ^ (pos & 7);
            float4 v = *(const float4*)(xp + (((long)b * PPIX + (h0 + ri) * 58 + ci) * 256 + g * 64 + chunkg * 8));
            *(float4*)&As[pos * 64 + chunkL * 8] = v;
        }
    }

    // per-lane pixel positions for the 7 px-subtiles (112 px = 2 image rows)
    int posb[7];
    #pragma unroll
    for (int pt = 0; pt < 7; pt++) {
        int p = pt * 16 + ln;              // 0..111
        int prow = (p >= 56) ? 1 : 0;
        int pcol = p - prow * 56;
        posb[pt] = prow * 58 + pcol + 1;
    }
    const bf16* wbase = wT + ((long)(g * 9) * 64 + wv * 16 + ln) * 64;

    __syncthreads();

    f32x4 acc[7] = {};
    #pragma unroll
    for (int tap = 0; tap < 9; tap++) {
        const int dr = tap / 3;
        const int dc = tap % 3 - 1;
        const bf16* wq = wbase + tap * 64 * 64;
        s16x8 B0 = *(const s16x8*)(wq + q * 8);
        s16x8 B1 = *(const s16x8*)(wq + 32 + q * 8);
        #pragma unroll
        for (int pt = 0; pt < 7; pt++) {
            int pos = posb[pt] + dr * 58 + dc;
            int off0 = pos * 64 + ((q ^ (pos & 7)) * 8);
            s16x8 a0 = *(const s16x8*)&As[off0];
            s16x8 a1 = *(const s16x8*)&As[off0 ^ 32];
            acc[pt] = __builtin_amdgcn_mfma_f32_16x16x32_bf16(a0, B0, acc[pt], 0, 0, 0);
            acc[pt] = __builtin_amdgcn_mfma_f32_16x16x32_bf16(a1, B1, acc[pt], 0, 0, 0);
        }
    }

    // ---- epilogue: BN+ReLU, transpose via LDS (aliases As), coalesced store ----
    __syncthreads();
    bf16* T = As;                          // 112 x 72 = 8064 elem < 14848
    int co = g * 64 + wv * 16 + ln;
    float sc = scale[co], bi = bias[co];
    #pragma unroll
    for (int pt = 0; pt < 7; pt++)
        #pragma unroll
        for (int r = 0; r < 4; r++)
            T[(pt * 16 + q * 4 + r) * 72 + wv * 16 + ln] = f2b(fmaxf(acc[pt][r] * sc + bi, 0.f));
    __syncthreads();
    int pimg0 = blockIdx.x * 112;
    #pragma unroll
    for (int i = 0; i < 4; i++) {
        int slot = t + i * 256;
        if (slot < 896) {
            int row = slot >> 3, cc = slot & 7;
            *(float4*)(kh + ((long)b * NPIX + pimg0 + row) * CDIM + g * 64 + cc * 8) = *(const float4*)&T[row * 72 + cc * 8];
        }
    }
    // ---- fused k-GAP partial: sum T over 112 rows per channel, 1 atomic/thread
    {
        int co_l = t & 63, rb = t >> 6;
        float s = 0.f;
        #pragma unroll
        for (int r = 0; r < 28; r++) s += b2f(T[(rb * 28 + r) * 72 + co_l]);
        atomicAdd(&gap[b * 256 + g * 64 + co_l], s);
    }
}

// ================= fused e1+c1 1x1-conv GEMM (independent, one launch) =========
// grid (49, 3, 16): by==0 -> e1 (K=512, M=128, ReLU, unpadded out);
// by in {1,2} -> c1 (K=256, M=256, no ReLU, PADDED out).
__global__ __launch_bounds__(256) void gemm_pair(
    const bf16* __restrict__ e1w, const bf16* __restrict__ c1w,
    const bf16* __restrict__ X0, const bf16* __restrict__ X1,
    const float* __restrict__ fold,
    bf16* __restrict__ Ye1, bf16* __restrict__ Yc1)
{
    int b = blockIdx.z;
    int p0 = blockIdx.x * 64;
    int by = blockIdx.y;
    const bf16* Wt; int K, M, m0; const float *scp, *bip; bf16* Y; bool relu;
    if (by == 0) { Wt = e1w; K = 512; M = 128; m0 = 0;
                   scp = fold + O_E1_S; bip = fold + O_E1_B; Y = Ye1; relu = true; }
    else         { Wt = c1w; K = 256; M = 256; m0 = (by - 1) * 128;
                   scp = fold + O_C1_S; bip = fold + O_C1_B; Y = Yc1; relu = false; }
    const int C0 = 256;

    __shared__ bf16 SH[64 * 72 + 128 * 72];   // As | Bs ; epilogue T aliases
    bf16* As = SH;
    bf16* Bs = SH + 64 * 72;
    int t = threadIdx.x;
    int wv = t >> 6, lane = t & 63, q = lane >> 4, ln = lane & 15;

    f32x4 acc[4][2] = {};
    for (int k0 = 0; k0 < K; k0 += 64) {
        __syncthreads();
        #pragma unroll
        for (int i = 0; i < 2; i++) {
            int slot = t + i * 256;
            int chunk = slot & 7, row = slot >> 3;
            int ch = k0 + chunk * 8;
            const bf16* src;
            if (ch < C0) {
                long pp = p0 + row;
                long pidx = (long)b * PPIX + pp + 2 * (pp / HDIM) + 59;
                src = X0 + pidx * C0 + ch;
            } else {
                src = X1 + ((long)b * NPIX + p0 + row) * 256 + (ch - C0);
            }
            *(float4*)&As[row * 72 + chunk * 8] = *(const float4*)src;
        }
        #pragma unroll
        for (int i = 0; i < 4; i++) {
            int slot = t + i * 256;
            int chunk = slot & 7, row = slot >> 3;
            *(float4*)&Bs[row * 72 + chunk * 8] = *(const float4*)(Wt + (long)(m0 + row) * K + k0 + chunk * 8);
        }
        __syncthreads();
        #pragma unroll
        for (int kk = 0; kk < 2; kk++) {
            s16x8 a[4];
            #pragma unroll
            for (int pt = 0; pt < 4; pt++)
                a[pt] = *(const s16x8*)&As[(pt * 16 + ln) * 72 + kk * 32 + q * 8];
            #pragma unroll
            for (int mi = 0; mi < 2; mi++) {
                s16x8 bb = *(const s16x8*)&Bs[(wv * 32 + mi * 16 + ln) * 72 + kk * 32 + q * 8];
                #pragma unroll
                for (int pt = 0; pt < 4; pt++)
                    acc[pt][mi] = __builtin_amdgcn_mfma_f32_16x16x32_bf16(a[pt], bb, acc[pt][mi], 0, 0, 0);
            }
        }
    }

    __syncthreads();
    bf16* T = SH;                     // 64 x 144
    #pragma unroll
    for (int mi = 0; mi < 2; mi++) {
        int m = m0 + wv * 32 + mi * 16 + ln;
        float sc = scp[m], bi = bip[m];
        #pragma unroll
        for (int pt = 0; pt < 4; pt++) {
            #pragma unroll
            for (int r = 0; r < 4; r++) {
                float v = acc[pt][mi][r] * sc + bi;
                if (relu) v = fmaxf(v, 0.f);
                T[(pt * 16 + q * 4 + r) * 144 + wv * 32 + mi * 16 + ln] = f2b(v);
            }
        }
    }
    __syncthreads();
    // store: 64 rows x 16 chunks of 16B (128 m-columns per tile)
    #pragma unroll
    for (int i = 0; i < 4; i++) {
        int slot = t + i * 256;
        int row = slot >> 4, chunk = slot & 15;
        long pp = p0 + row;
        long pidx = (by == 0) ? ((long)b * NPIX + pp)
                              : ((long)b * PPIX + pp + 2 * (pp / HDIM) + 59);
        *(float4*)(Y + pidx * M + m0 + chunk * 8) = *(const float4*)&T[row * 144 + chunk * 8];
    }
}

// ================= 1x1 conv GEMM (e2): +bias + fused GN partial sums ===========
// grid (49, 3, 16), block 256 (4 waves)
__global__ __launch_bounds__(256) void mfma_gemm_e2(
    const bf16* __restrict__ Wt, const bf16* __restrict__ X0,
    const float* __restrict__ bias,
    bf16* __restrict__ Y, float* __restrict__ gnsum)
{
    const int K = 128, M = 288;
    int b = blockIdx.z;
    int p0 = blockIdx.x * 64;
    int m0 = blockIdx.y * 128;
    __shared__ bf16 SH[64 * 72 + 128 * 72];
    bf16* As = SH;
    bf16* Bs = SH + 64 * 72;
    __shared__ float gs[64];
    int t = threadIdx.x;
    int wv = t >> 6, lane = t & 63, q = lane >> 4, ln = lane & 15;
    if (t < 64) gs[t] = 0.f;

    f32x4 acc[4][2] = {};
    for (int k0 = 0; k0 < K; k0 += 64) {
        __syncthreads();
        #pragma unroll
        for (int i = 0; i < 2; i++) {
            int slot = t + i * 256;
            int chunk = slot & 7, row = slot >> 3;
            int ch = k0 + chunk * 8;
            *(float4*)&As[row * 72 + chunk * 8] = *(const float4*)(X0 + ((long)b * NPIX + p0 + row) * K + ch);
        }
        #pragma unroll
        for (int i = 0; i < 4; i++) {
            int slot = t + i * 256;
            int chunk = slot & 7, row = slot >> 3;
            int m = m0 + row;
            float4 v = {0.f, 0.f, 0.f, 0.f};
            if (m < M) v = *(const float4*)(Wt + (long)m * K + k0 + chunk * 8);
            *(float4*)&Bs[row * 72 + chunk * 8] = v;
        }
        __syncthreads();
        #pragma unroll
        for (int kk = 0; kk < 2; kk++) {
            s16x8 a[4];
            #pragma unroll
            for (int pt = 0; pt < 4; pt++)
                a[pt] = *(const s16x8*)&As[(pt * 16 + ln) * 72 + kk * 32 + q * 8];
            #pragma unroll
            for (int mi = 0; mi < 2; mi++) {
                s16x8 bb = *(const s16x8*)&Bs[(wv * 32 + mi * 16 + ln) * 72 + kk * 32 + q * 8];
                #pragma unroll
                for (int pt = 0; pt < 4; pt++)
                    acc[pt][mi] = __builtin_amdgcn_mfma_f32_16x16x32_bf16(a[pt], bb, acc[pt][mi], 0, 0, 0);
            }
        }
    }

    __syncthreads();
    bf16* T = SH;
    #pragma unroll
    for (int mi = 0; mi < 2; mi++) {
        int m = m0 + wv * 32 + mi * 16 + ln;
        int mc = (m > M - 1) ? (M - 1) : m;
        float bi = bias[mc];
        float ps = 0.f, pq = 0.f;
        #pragma unroll
        for (int pt = 0; pt < 4; pt++) {
            #pragma unroll
            for (int r = 0; r < 4; r++) {
                float v = acc[pt][mi][r] + bi;
                ps += v; pq += v * v;
                T[(pt * 16 + q * 4 + r) * 144 + wv * 32 + mi * 16 + ln] = f2b(v);
            }
        }
        if (m < M) {
            int grp = m / 9;
            atomicAdd(&gs[grp * 2], ps);
            atomicAdd(&gs[grp * 2 + 1], pq);
        }
    }
    __syncthreads();
    #pragma unroll
    for (int i = 0; i < 4; i++) {
        int slot = t + i * 256;
        int chunk = slot & 15, row = slot >> 4;
        int m = m0 + chunk * 8;
        if (m + 8 <= M)
            *(float4*)(Y + ((long)b * NPIX + p0 + row) * M + m) = *(const float4*)&T[row * 144 + chunk * 8];
    }
    if (t < 64) atomicAdd(&gnsum[b * 64 + t], gs[t]);
}

// ================= dynamic local conv + inline GN + BN(b2) + swish + y-GAP =====
// (r6 variant — fastest measured of the padded-xq family)
__global__ __launch_bounds__(256) void dynconv(
    const bf16* __restrict__ xq, const bf16* __restrict__ wemb,
    const float* __restrict__ gnsum,
    const float* __restrict__ gng, const float* __restrict__ gnb,
    const float* __restrict__ b2s, const float* __restrict__ b2b,
    bf16* __restrict__ y, float* __restrict__ gap)
{
    int t = threadIdx.x;
    int grp = t & 31, pl = t >> 5;
    int bid = blockIdx.x;                  // 16 b x 392 tiles
    int b = bid / 392;
    int p0 = (bid - b * 392) * 8;
    int p = p0 + pl;
    int h = p / HDIM, w = p - h * HDIM;    // all 8 pixels in one row (8 | 56)

    __shared__ bf16 WE[2304];              // 8 px x 288, contiguous slab
    __shared__ float SA[288], SC[288];
    __shared__ float R[8][256];

    {
        const bf16* src = wemb + (long)(b * NPIX + p0) * 288;
        #pragma unroll
        for (int i = 0; i < 2; i++) {
            int s = t + i * 256;
            if (s < 288) *(float4*)&WE[s * 8] = *(const float4*)(src + s * 8);
        }
    }
    for (int s = t; s < 288; s += 256) {
        int g2 = s / 9;
        float S = gnsum[b * 64 + g2 * 2], Q = gnsum[b * 64 + g2 * 2 + 1];
        float mu = S * (1.f / 28224.f);
        float var = Q * (1.f / 28224.f) - mu * mu;
        float rs = rsqrtf(fmaxf(var, 0.f) + 1e-5f);
        float a = rs * gng[s];
        SA[s] = a;
        SC[s] = gnb[s] - mu * a;
    }
    __syncthreads();

    // ---- 9 unconditional tap loads from padded xq ----
    long base = ((long)b * PPIX + (h + 1) * 58 + (w + 1)) * 256 + grp * 8;
    const bf16* rm = xq + base - 58 * 256;
    const bf16* rc = xq + base;
    const bf16* rq = xq + base + 58 * 256;
    s16x8 xv[9];
    xv[0] = *(const s16x8*)(rm - 256); xv[1] = *(const s16x8*)rm; xv[2] = *(const s16x8*)(rm + 256);
    xv[3] = *(const s16x8*)(rc - 256); xv[4] = *(const s16x8*)rc; xv[5] = *(const s16x8*)(rc + 256);
    xv[6] = *(const s16x8*)(rq - 256); xv[7] = *(const s16x8*)rq; xv[8] = *(const s16x8*)(rq + 256);

    float acc[8] = {};
    #pragma unroll
    for (int tp = 0; tp < 9; tp++) {
        int wi = grp * 9 + tp;
        float wt = b2f(WE[pl * 288 + wi]) * SA[wi] + SC[wi];
        const bf16* xb = (const bf16*)&xv[tp];
        #pragma unroll
        for (int i = 0; i < 8; i++) acc[i] += b2f(xb[i]) * wt;
    }

    bf16 outv[8];
    float sv[8];
    #pragma unroll
    for (int i = 0; i < 8; i++) {
        int c = grp * 8 + i;
        float v = acc[i] * b2s[c] + b2b[c];
        float sw = v / (1.f + __expf(-v));
        sv[i] = sw;
        outv[i] = f2b(sw);
    }
    *(float4*)(y + ((long)b * NPIX + p) * CDIM + grp * 8) = *(const float4*)outv;

    // ---- fused y-GAP: reduce 8 pixels per block in LDS, 1 atomic/thread ----
    #pragma unroll
    for (int i = 0; i < 8; i++) R[pl][grp * 8 + i] = sv[i];
    __syncthreads();
    float s = 0.f;
    #pragma unroll
    for (int j = 0; j < 8; j++) s += R[j][t];
    atomicAdd(&gap[b * 256 + t], s);
}

// ================= split attention ============================================
__global__ void attnk(const float* __restrict__ gap,
                      const float* __restrict__ s1w, const float* __restrict__ s1b,
                      const float* __restrict__ s1s, const float* __restrict__ s1bi,
                      const float* __restrict__ s2w, const float* __restrict__ s2b,
                      float* __restrict__ att)
{
    int b = blockIdx.x, t = threadIdx.x;   // 128 threads
    __shared__ float g[256], a1[128];
    for (int i = t; i < 256; i += 128) g[i] = gap[b * 256 + i] * (1.f / NPIX);
    __syncthreads();
    float s = 0.f;
    for (int ci = 0; ci < 256; ci++) s += s1w[t * 256 + ci] * g[ci];
    s += s1b[t];
    s = s * s1s[t] + s1bi[t];
    a1[t] = fmaxf(s, 0.f);
    __syncthreads();
    for (int c = t; c < 256; c += 128) {
        float v0 = s2b[2 * c], v1 = s2b[2 * c + 1];
        for (int ci = 0; ci < 128; ci++) {
            float av = a1[ci];
            v0 += s2w[(2 * c) * 128 + ci] * av;
            v1 += s2w[(2 * c + 1) * 128 + ci] * av;
        }
        float m = fmaxf(v0, v1);
        float e0 = __expf(v0 - m), e1 = __expf(v1 - m);
        float inv = 1.f / (e0 + e1);
        att[(b * 256 + c) * 2 + 0] = e0 * inv;
        att[(b * 256 + c) * 2 + 1] = e1 * inv;
    }
}

// ================= final: combine + NHWC->NCHW fp32 out =======================
__global__ __launch_bounds__(256) void finalk(
    const bf16* __restrict__ y, const bf16* __restrict__ k,
    const float* __restrict__ att, float* __restrict__ out)
{
    int b = blockIdx.z, c0 = blockIdx.y * 64, p0 = blockIdx.x * 64;
    __shared__ bf16 Ys[64][72], Ks[64][72];
    int t = threadIdx.x;
    #pragma unroll
    for (int i = 0; i < 2; i++) {
        int slot = t + i * 256;
        int row = slot >> 3, cc = slot & 7;
        long off = ((long)b * NPIX + p0 + row) * CDIM + c0 + cc * 8;
        *(float4*)&Ys[row][cc * 8] = *(const float4*)(y + off);
        *(float4*)&Ks[row][cc * 8] = *(const float4*)(k + off);
    }
    __syncthreads();
    int c_l = t >> 2, pc = t & 3;
    int c = c0 + c_l;
    float a0 = att[(b * 256 + c) * 2], a1 = att[(b * 256 + c) * 2 + 1];
    float4 o[4];
    float* of = (float*)o;
    #pragma unroll
    for (int j = 0; j < 16; j++) {
        int p = pc * 16 + j;
        of[j] = b2f(Ys[p][c_l]) * a0 + b2f(Ks[p][c_l]) * a1;
    }
    float* dst = out + ((long)b * CDIM + c) * NPIX + p0 + pc * 16;
    #pragma unroll
    for (int j = 0; j < 4; j++) ((float4*)dst)[j] = o[j];
}

extern "C" void kernel_launch(void* const* d_in, const int* in_sizes, int n_in,
                              void* d_out, int out_size, void* d_ws, size_t ws_size,
                              hipStream_t stream)
{
    const float* x    = (const float*)d_in[0];
    const float* ke_w = (const float*)d_in[1];
    const float* ke_g = (const float*)d_in[2];
    const float* ke_b = (const float*)d_in[3];
    const float* ke_m = (const float*)d_in[4];
    const float* ke_v = (const float*)d_in[5];
    const float* e1_w = (const float*)d_in[6];
    const float* e1_g = (const float*)d_in[7];
    const float* e1_b = (const float*)d_in[8];
    const float* e1_m = (const float*)d_in[9];
    const float* e1_v = (const float*)d_in[10];
    const float* e2_w = (const float*)d_in[11];
    const float* e2_b = (const float*)d_in[12];
    const float* gng  = (const float*)d_in[13];
    const float* gnb  = (const float*)d_in[14];
    const float* c1_w = (const float*)d_in[15];
    const float* c1_g = (const float*)d_in[16];
    const float* c1_b = (const float*)d_in[17];
    const float* c1_m = (const float*)d_in[18];
    const float* c1_v = (const float*)d_in[19];
    const float* b2_g = (const float*)d_in[20];
    const float* b2_b = (const float*)d_in[21];
    const float* b2_m = (const float*)d_in[22];
    const float* b2_v = (const float*)d_in[23];
    const float* s1_w = (const float*)d_in[24];
    const float* s1_b = (const float*)d_in[25];
    const float* s1_g = (const float*)d_in[26];
    const float* s1_bb= (const float*)d_in[27];
    const float* s1_m = (const float*)d_in[28];
    const float* s1_v = (const float*)d_in[29];
    const float* s2_w = (const float*)d_in[30];
    const float* s2_b = (const float*)d_in[31];

    float* fold = (float*)d_ws;
    bf16* wsb   = (bf16*)((char*)d_ws + 65536);
    bf16* xh   = wsb;                     // padded: 16*3364*256 = 13,778,944
    bf16* kh   = xh + 13778944L;          // 12,845,056
    bf16* wemb = kh + 12845056L;          // 14,450,688
    bf16* w1   = wemb + 14450688L;        // 6,422,528 (e1 out)
    bf16* kewT = w1 + 6422528L;           // 147,456
    bf16* e1wb = kewT + 147456L;          // 65,536
    bf16* e2wb = e1wb + 65536L;           // 36,864
    bf16* c1wb = e2wb + 36864L;           // 65,536
    bf16* xq   = c1wb + 65536L;           // padded: 13,778,944
    bf16* yb   = xh;                      // alias (xh dead after gemm_pair; unpadded)

    prep<<<dim3(2165), dim3(256), 0, stream>>>(
        ke_w, e1_w, e2_w, c1_w,
        ke_g, ke_b, ke_m, ke_v, e1_g, e1_b, e1_m, e1_v, e2_b,
        c1_g, c1_b, c1_m, c1_v, b2_g, b2_b, b2_m, b2_v,
        s1_g, s1_bb, s1_m, s1_v,
        kewT, e1wb, e2wb, c1wb, fold, xh, xq);

    cvt_x<<<dim3(49, 4, 16), dim3(256), 0, stream>>>(x, xh);

    gconv_mfma<<<dim3(28, 4, 16), dim3(256), 0, stream>>>(
        xh, kewT, fold + O_KE_S, fold + O_KE_B, kh, fold + O_GAP);

    gemm_pair<<<dim3(49, 3, 16), dim3(256), 0, stream>>>(
        e1wb, c1wb, xh, kh, fold, w1, xq);

    mfma_gemm_e2<<<dim3(49, 3, 16), dim3(256), 0, stream>>>(
        e2wb, w1, fold + O_E2B, wemb, fold + O_GNS);

    dynconv<<<dim3(6272), dim3(256), 0, stream>>>(
        xq, wemb, fold + O_GNS, gng, gnb,
        fold + O_B2_S, fold + O_B2_B, yb, fold + O_GAP);

    attnk<<<dim3(16), dim3(128), 0, stream>>>(
        fold + O_GAP, s1_w, s1_b, fold + O_S1_S, fold + O_S1_B, s2_w, s2_b, fold + O_ATT);

    finalk<<<dim3(49, 4, 16), dim3(256), 0, stream>>>(yb, kh, fold + O_ATT, (float*)d_out);
}

// Round 10
// 333.035 us; speedup vs baseline: 1.0849x; 1.0585x over previous
//
#include <hip/hip_runtime.h>
#include <hip/hip_bf16.h>

typedef __hip_bfloat16 bf16;
typedef float f32x4 __attribute__((ext_vector_type(4)));
typedef short s16x8 __attribute__((ext_vector_type(8)));

#define NPIX 3136   // 56*56
#define HDIM 56
#define CDIM 256
#define PPIX 3364   // 58*58 padded

static __device__ __forceinline__ float b2f(bf16 v){ return __bfloat162float(v); }
static __device__ __forceinline__ bf16  f2b(float v){ return __float2bfloat16(v); }

// ---- fold region float offsets (fold = 128 KB = 32768 floats) ----
#define O_KE_S 0
#define O_KE_B 256
#define O_E1_S 512
#define O_E1_B 640
#define O_C1_S 768
#define O_C1_B 1024
#define O_B2_S 1280
#define O_B2_B 1536
#define O_S1_S 1792
#define O_S1_B 1920
#define O_E2B  2048
#define O_GNS  2336   // gnsum[b][grp][2] : 16*32*2 = 1024 floats
#define O_GAP  3360   // raw sums of (y+k) over pixels, scaled by 1/NPIX in attnk
#define O_ATT  7456   // 16*256*2 = 8192 -> ends 15648
#define O_SA   15872  // SA/SC folded GN affine: [b][576] (SA 0..288 | SC 288..576), ends 25088

// ================= prep: weight converts + BN folds + zeros + pad borders ======
__global__ void prep(
    const float* __restrict__ kew, const float* __restrict__ e1w,
    const float* __restrict__ e2w, const float* __restrict__ c1w,
    const float* keg, const float* keb, const float* kem, const float* kev,
    const float* e1g, const float* e1b, const float* e1m, const float* e1v,
    const float* e2b,
    const float* c1g, const float* c1b, const float* c1m, const float* c1v,
    const float* b2g, const float* b2b, const float* b2m, const float* b2v,
    const float* s1g, const float* s1bb, const float* s1m, const float* s1v,
    bf16* kewT, bf16* e1wb, bf16* e2wb, bf16* c1wb, float* o,
    bf16* xh, bf16* xq)
{
    int bid = blockIdx.x, t = threadIdx.x;
    if (bid < 576) {                       // kewT: (256,64,3,3) -> [g][tap][co_l][ci]
        int i = bid * 256 + t;
        int ci = i & 63, co_l = (i >> 6) & 63;
        int gt = i >> 12;
        int tap = gt % 9, g = gt / 9;
        int co = g * 64 + co_l;
        kewT[i] = f2b(kew[(co * 64 + ci) * 9 + tap]);
    } else if (bid < 832) {
        int i = (bid - 576) * 256 + t; e1wb[i] = f2b(e1w[i]);
    } else if (bid < 976) {
        int i = (bid - 832) * 256 + t; e2wb[i] = f2b(e2w[i]);
    } else if (bid < 1232) {
        int i = (bid - 976) * 256 + t; c1wb[i] = f2b(c1w[i]);
    } else if (bid == 1232) {
        const float eps = 1e-5f;
        {
            float s = keg[t] * rsqrtf(kev[t] + eps);
            o[O_KE_S + t] = s; o[O_KE_B + t] = keb[t] - kem[t] * s;
            s = c1g[t] * rsqrtf(c1v[t] + eps);
            o[O_C1_S + t] = s; o[O_C1_B + t] = c1b[t] - c1m[t] * s;
            s = b2g[t] * rsqrtf(b2v[t] + eps);
            o[O_B2_S + t] = s; o[O_B2_B + t] = b2b[t] - b2m[t] * s;
        }
        if (t < 128) {
            float s = e1g[t] * rsqrtf(e1v[t] + eps);
            o[O_E1_S + t] = s; o[O_E1_B + t] = e1b[t] - e1m[t] * s;
            s = s1g[t] * rsqrtf(s1v[t] + eps);
            o[O_S1_S + t] = s; o[O_S1_B + t] = s1bb[t] - s1m[t] * s;
        }
        for (int i = t; i < 288; i += 256) o[O_E2B + i] = e2b[i];
    } else if (bid < 1253) {                // zeros: gnsum (1024) + gap (4096)
        int j = (bid - 1233) * 256 + t;
        if (j < 1024) o[O_GNS + j] = 0.f;
        else if (j < 5120) o[O_GAP + j - 1024] = 0.f;
    } else {                                // pad borders of xh and xq (zero)
        int j = (bid - 1253) * 256 + t;     // 0 .. 233471 = 2*16*7296
        bf16* arr = (j >= 116736) ? xq : xh;
        int r = j % 116736;
        int img = r / 7296;
        int s = r % 7296;
        int pi = s >> 5, cc = s & 31;
        int pos;
        if (pi < 58)       pos = pi;                     // top row
        else if (pi < 116) pos = 57 * 58 + (pi - 58);    // bottom row
        else if (pi < 172) pos = (pi - 115) * 58;        // left col rows 1..56
        else               pos = (pi - 171) * 58 + 57;   // right col rows 1..56
        float4 z = {0.f, 0.f, 0.f, 0.f};
        *(float4*)(arr + ((long)img * PPIX + pos) * 256 + cc * 8) = z;
    }
}

// ================= x: fp32 NCHW -> bf16 NHWC (58x58 zero-padded interior) ======
// grid (49, 4, 16): 64px x 64ch tile per block.
__global__ __launch_bounds__(256) void cvt_x(const float* __restrict__ x, bf16* __restrict__ xh)
{
    int b = blockIdx.z;
    int c0 = blockIdx.y * 64;
    int p0 = blockIdx.x * 64;
    __shared__ bf16 T[64][72];
    int t = threadIdx.x;
    #pragma unroll
    for (int it = 0; it < 4; it++) {
        int slot = t + it * 256;           // 0..1023
        int cl = slot >> 4, ch4 = slot & 15;
        float4 v = *(const float4*)(x + ((long)b * CDIM + c0 + cl) * NPIX + p0 + ch4 * 4);
        T[ch4 * 4 + 0][cl] = f2b(v.x);
        T[ch4 * 4 + 1][cl] = f2b(v.y);
        T[ch4 * 4 + 2][cl] = f2b(v.z);
        T[ch4 * 4 + 3][cl] = f2b(v.w);
    }
    __syncthreads();
    #pragma unroll
    for (int it = 0; it < 2; it++) {
        int slot = t + it * 256;           // 0..511
        int p = slot >> 3, cc = slot & 7;
        int pl = p0 + p;
        int h = pl / HDIM, w = pl - h * HDIM;
        *(float4*)(xh + ((long)b * PPIX + (h + 1) * 58 + (w + 1)) * 256 + c0 + cc * 8) = *(const float4*)&T[p][cc * 8];
    }
}

// ================= MERGED: grouped 3x3 conv  ||  c1 1x1 GEMM ===================
// grid (210, 1, 16): bx<112 -> gconv (tile=bx>>2, group=bx&3);
//                    bx>=112 -> c1 (mt=(bx-112)&1, px=(bx-112)>>1).
// Both read xh; independent outputs (kh + gap-k vs padded xq). One launch so
// the scheduler overlaps their staging/MFMA phases.
__global__ __launch_bounds__(256) void gconv_c1(
    const bf16* __restrict__ xp, const bf16* __restrict__ wT,
    const float* __restrict__ kes, const float* __restrict__ keb,
    const bf16* __restrict__ c1w,
    const float* __restrict__ c1s, const float* __restrict__ c1b,
    bf16* __restrict__ kh, bf16* __restrict__ xq, float* __restrict__ gap)
{
    __shared__ bf16 SH[232 * 64];          // 14848 elems; both branches fit
    int b = blockIdx.z;
    int bx = blockIdx.x;
    int t = threadIdx.x;
    int wv = t >> 6, lane = t & 63, q = lane >> 4, ln = lane & 15;

    if (bx < 112) {
        // ---------------- gconv branch ----------------
        int hx = bx >> 2, g = bx & 3;
        int h0 = hx * 2;
        bf16* As = SH;
        #pragma unroll
        for (int i = 0; i < 8; i++) {
            int slot = t + i * 256;
            if (slot < 1856) {
                int pos = slot >> 3, chunkL = slot & 7;
                int ri = pos / 58, ci = pos - ri * 58;
                int chunkg = chunkL ^ (pos & 7);
                float4 v = *(const float4*)(xp + (((long)b * PPIX + (h0 + ri) * 58 + ci) * 256 + g * 64 + chunkg * 8));
                *(float4*)&As[pos * 64 + chunkL * 8] = v;
            }
        }
        int posb[7];
        #pragma unroll
        for (int pt = 0; pt < 7; pt++) {
            int p = pt * 16 + ln;
            int prow = (p >= 56) ? 1 : 0;
            int pcol = p - prow * 56;
            posb[pt] = prow * 58 + pcol + 1;
        }
        const bf16* wbase = wT + ((long)(g * 9) * 64 + wv * 16 + ln) * 64;
        __syncthreads();

        f32x4 acc[7] = {};
        #pragma unroll
        for (int tap = 0; tap < 9; tap++) {
            const int dr = tap / 3;
            const int dc = tap % 3 - 1;
            const bf16* wq = wbase + tap * 64 * 64;
            s16x8 B0 = *(const s16x8*)(wq + q * 8);
            s16x8 B1 = *(const s16x8*)(wq + 32 + q * 8);
            #pragma unroll
            for (int pt = 0; pt < 7; pt++) {
                int pos = posb[pt] + dr * 58 + dc;
                int off0 = pos * 64 + ((q ^ (pos & 7)) * 8);
                s16x8 a0 = *(const s16x8*)&As[off0];
                s16x8 a1 = *(const s16x8*)&As[off0 ^ 32];
                acc[pt] = __builtin_amdgcn_mfma_f32_16x16x32_bf16(a0, B0, acc[pt], 0, 0, 0);
                acc[pt] = __builtin_amdgcn_mfma_f32_16x16x32_bf16(a1, B1, acc[pt], 0, 0, 0);
            }
        }
        __syncthreads();
        bf16* T = As;                      // 112 x 72
        int co = g * 64 + wv * 16 + ln;
        float sc = kes[co], bi = keb[co];
        #pragma unroll
        for (int pt = 0; pt < 7; pt++)
            #pragma unroll
            for (int r = 0; r < 4; r++)
                T[(pt * 16 + q * 4 + r) * 72 + wv * 16 + ln] = f2b(fmaxf(acc[pt][r] * sc + bi, 0.f));
        __syncthreads();
        int pimg0 = hx * 112;
        #pragma unroll
        for (int i = 0; i < 4; i++) {
            int slot = t + i * 256;
            if (slot < 896) {
                int row = slot >> 3, cc = slot & 7;
                *(float4*)(kh + ((long)b * NPIX + pimg0 + row) * CDIM + g * 64 + cc * 8) = *(const float4*)&T[row * 72 + cc * 8];
            }
        }
        {
            int co_l = t & 63, rb = t >> 6;
            float s = 0.f;
            #pragma unroll
            for (int r = 0; r < 28; r++) s += b2f(T[(rb * 28 + r) * 72 + co_l]);
            atomicAdd(&gap[b * 256 + g * 64 + co_l], s);
        }
    } else {
        // ---------------- c1 branch (K=256, M=256, padded out) ----------------
        int px = bx - 112;
        int mt = px & 1; px >>= 1;         // px in [0,49)
        int p0 = px * 64;
        int m0 = mt * 128;
        bf16* As = SH;                     // 64 x 72
        bf16* Bs = SH + 64 * 72;           // 128 x 72

        f32x4 acc[4][2] = {};
        for (int k0 = 0; k0 < 256; k0 += 64) {
            __syncthreads();
            #pragma unroll
            for (int i = 0; i < 2; i++) {
                int slot = t + i * 256;
                int chunk = slot & 7, row = slot >> 3;
                long pp = p0 + row;
                long pidx = (long)b * PPIX + pp + 2 * (pp / HDIM) + 59;
                *(float4*)&As[row * 72 + chunk * 8] = *(const float4*)(xp + pidx * 256 + k0 + chunk * 8);
            }
            #pragma unroll
            for (int i = 0; i < 4; i++) {
                int slot = t + i * 256;
                int chunk = slot & 7, row = slot >> 3;
                *(float4*)&Bs[row * 72 + chunk * 8] = *(const float4*)(c1w + (long)(m0 + row) * 256 + k0 + chunk * 8);
            }
            __syncthreads();
            #pragma unroll
            for (int kk = 0; kk < 2; kk++) {
                s16x8 a[4];
                #pragma unroll
                for (int pt = 0; pt < 4; pt++)
                    a[pt] = *(const s16x8*)&As[(pt * 16 + ln) * 72 + kk * 32 + q * 8];
                #pragma unroll
                for (int mi = 0; mi < 2; mi++) {
                    s16x8 bb = *(const s16x8*)&Bs[(wv * 32 + mi * 16 + ln) * 72 + kk * 32 + q * 8];
                    #pragma unroll
                    for (int pt = 0; pt < 4; pt++)
                        acc[pt][mi] = __builtin_amdgcn_mfma_f32_16x16x32_bf16(a[pt], bb, acc[pt][mi], 0, 0, 0);
                }
            }
        }
        __syncthreads();
        bf16* T = SH;                      // 64 x 144
        #pragma unroll
        for (int mi = 0; mi < 2; mi++) {
            int m = m0 + wv * 32 + mi * 16 + ln;
            float sc = c1s[m], bi = c1b[m];
            #pragma unroll
            for (int pt = 0; pt < 4; pt++) {
                #pragma unroll
                for (int r = 0; r < 4; r++) {
                    float v = acc[pt][mi][r] * sc + bi;
                    T[(pt * 16 + q * 4 + r) * 144 + wv * 32 + mi * 16 + ln] = f2b(v);
                }
            }
        }
        __syncthreads();
        #pragma unroll
        for (int i = 0; i < 4; i++) {
            int slot = t + i * 256;
            int row = slot >> 4, chunk = slot & 15;
            long pp = p0 + row;
            long pidx = (long)b * PPIX + pp + 2 * (pp / HDIM) + 59;
            *(float4*)(xq + pidx * 256 + m0 + chunk * 8) = *(const float4*)&T[row * 144 + chunk * 8];
        }
    }
}

// ================= e1 1x1-conv GEMM (K=512: xh | kh, M=128, ReLU) ==============
// grid (49, 16), block 256 (4 waves)
__global__ __launch_bounds__(256) void mfma_gemm_e1(
    const bf16* __restrict__ Wt, const bf16* __restrict__ X0, const bf16* __restrict__ X1,
    const float* __restrict__ scale, const float* __restrict__ bias,
    bf16* __restrict__ Y)
{
    int b = blockIdx.y;
    int p0 = blockIdx.x * 64;
    __shared__ bf16 SH[64 * 72 + 128 * 72];
    bf16* As = SH;
    bf16* Bs = SH + 64 * 72;
    int t = threadIdx.x;
    int wv = t >> 6, lane = t & 63, q = lane >> 4, ln = lane & 15;

    f32x4 acc[4][2] = {};
    for (int k0 = 0; k0 < 512; k0 += 64) {
        __syncthreads();
        #pragma unroll
        for (int i = 0; i < 2; i++) {
            int slot = t + i * 256;
            int chunk = slot & 7, row = slot >> 3;
            int ch = k0 + chunk * 8;
            const bf16* src;
            if (ch < 256) {
                long pp = p0 + row;
                long pidx = (long)b * PPIX + pp + 2 * (pp / HDIM) + 59;
                src = X0 + pidx * 256 + ch;
            } else {
                src = X1 + ((long)b * NPIX + p0 + row) * 256 + (ch - 256);
            }
            *(float4*)&As[row * 72 + chunk * 8] = *(const float4*)src;
        }
        #pragma unroll
        for (int i = 0; i < 4; i++) {
            int slot = t + i * 256;
            int chunk = slot & 7, row = slot >> 3;
            *(float4*)&Bs[row * 72 + chunk * 8] = *(const float4*)(Wt + (long)row * 512 + k0 + chunk * 8);
        }
        __syncthreads();
        #pragma unroll
        for (int kk = 0; kk < 2; kk++) {
            s16x8 a[4];
            #pragma unroll
            for (int pt = 0; pt < 4; pt++)
                a[pt] = *(const s16x8*)&As[(pt * 16 + ln) * 72 + kk * 32 + q * 8];
            #pragma unroll
            for (int mi = 0; mi < 2; mi++) {
                s16x8 bb = *(const s16x8*)&Bs[(wv * 32 + mi * 16 + ln) * 72 + kk * 32 + q * 8];
                #pragma unroll
                for (int pt = 0; pt < 4; pt++)
                    acc[pt][mi] = __builtin_amdgcn_mfma_f32_16x16x32_bf16(a[pt], bb, acc[pt][mi], 0, 0, 0);
            }
        }
    }
    __syncthreads();
    bf16* T = SH;                     // 64 x 144
    #pragma unroll
    for (int mi = 0; mi < 2; mi++) {
        int m = wv * 32 + mi * 16 + ln;
        float sc = scale[m], bi = bias[m];
        #pragma unroll
        for (int pt = 0; pt < 4; pt++) {
            #pragma unroll
            for (int r = 0; r < 4; r++) {
                float v = fmaxf(acc[pt][mi][r] * sc + bi, 0.f);
                T[(pt * 16 + q * 4 + r) * 144 + m] = f2b(v);
            }
        }
    }
    __syncthreads();
    #pragma unroll
    for (int i = 0; i < 4; i++) {
        int slot = t + i * 256;
        int row = slot >> 4, chunk = slot & 15;
        *(float4*)(Y + ((long)b * NPIX + p0 + row) * 128 + chunk * 8) = *(const float4*)&T[row * 144 + chunk * 8];
    }
}

// ================= 1x1 conv GEMM (e2): +bias + fused GN partial sums ===========
// grid (49, 3, 16), block 256 (4 waves)
__global__ __launch_bounds__(256) void mfma_gemm_e2(
    const bf16* __restrict__ Wt, const bf16* __restrict__ X0,
    const float* __restrict__ bias,
    bf16* __restrict__ Y, float* __restrict__ gnsum)
{
    const int K = 128, M = 288;
    int b = blockIdx.z;
    int p0 = blockIdx.x * 64;
    int m0 = blockIdx.y * 128;
    __shared__ bf16 SH[64 * 72 + 128 * 72];
    bf16* As = SH;
    bf16* Bs = SH + 64 * 72;
    __shared__ float gs[64];
    int t = threadIdx.x;
    int wv = t >> 6, lane = t & 63, q = lane >> 4, ln = lane & 15;
    if (t < 64) gs[t] = 0.f;

    f32x4 acc[4][2] = {};
    for (int k0 = 0; k0 < K; k0 += 64) {
        __syncthreads();
        #pragma unroll
        for (int i = 0; i < 2; i++) {
            int slot = t + i * 256;
            int chunk = slot & 7, row = slot >> 3;
            int ch = k0 + chunk * 8;
            *(float4*)&As[row * 72 + chunk * 8] = *(const float4*)(X0 + ((long)b * NPIX + p0 + row) * K + ch);
        }
        #pragma unroll
        for (int i = 0; i < 4; i++) {
            int slot = t + i * 256;
            int chunk = slot & 7, row = slot >> 3;
            int m = m0 + row;
            float4 v = {0.f, 0.f, 0.f, 0.f};
            if (m < M) v = *(const float4*)(Wt + (long)m * K + k0 + chunk * 8);
            *(float4*)&Bs[row * 72 + chunk * 8] = v;
        }
        __syncthreads();
        #pragma unroll
        for (int kk = 0; kk < 2; kk++) {
            s16x8 a[4];
            #pragma unroll
            for (int pt = 0; pt < 4; pt++)
                a[pt] = *(const s16x8*)&As[(pt * 16 + ln) * 72 + kk * 32 + q * 8];
            #pragma unroll
            for (int mi = 0; mi < 2; mi++) {
                s16x8 bb = *(const s16x8*)&Bs[(wv * 32 + mi * 16 + ln) * 72 + kk * 32 + q * 8];
                #pragma unroll
                for (int pt = 0; pt < 4; pt++)
                    acc[pt][mi] = __builtin_amdgcn_mfma_f32_16x16x32_bf16(a[pt], bb, acc[pt][mi], 0, 0, 0);
            }
        }
    }

    __syncthreads();
    bf16* T = SH;
    #pragma unroll
    for (int mi = 0; mi < 2; mi++) {
        int m = m0 + wv * 32 + mi * 16 + ln;
        int mc = (m > M - 1) ? (M - 1) : m;
        float bi = bias[mc];
        float ps = 0.f, pq = 0.f;
        #pragma unroll
        for (int pt = 0; pt < 4; pt++) {
            #pragma unroll
            for (int r = 0; r < 4; r++) {
                float v = acc[pt][mi][r] + bi;
                ps += v; pq += v * v;
                T[(pt * 16 + q * 4 + r) * 144 + wv * 32 + mi * 16 + ln] = f2b(v);
            }
        }
        if (m < M) {
            int grp = m / 9;
            atomicAdd(&gs[grp * 2], ps);
            atomicAdd(&gs[grp * 2 + 1], pq);
        }
    }
    __syncthreads();
    #pragma unroll
    for (int i = 0; i < 4; i++) {
        int slot = t + i * 256;
        int chunk = slot & 15, row = slot >> 4;
        int m = m0 + chunk * 8;
        if (m + 8 <= M)
            *(float4*)(Y + ((long)b * NPIX + p0 + row) * M + m) = *(const float4*)&T[row * 144 + chunk * 8];
    }
    if (t < 64) atomicAdd(&gnsum[b * 64 + t], gs[t]);
}

// ================= gnfold: GN affine folds, once per (b, grp, tap) =============
__global__ void gnfold(const float* __restrict__ gnsum,
                       const float* __restrict__ gng, const float* __restrict__ gnb,
                       float* __restrict__ o)
{
    int b = blockIdx.x, t = threadIdx.x;
    for (int s = t; s < 288; s += 256) {
        int g2 = s / 9;
        float S = gnsum[b * 64 + g2 * 2], Q = gnsum[b * 64 + g2 * 2 + 1];
        float mu = S * (1.f / 28224.f);
        float var = Q * (1.f / 28224.f) - mu * mu;
        float rs = rsqrtf(fmaxf(var, 0.f) + 1e-5f);
        float a = rs * gng[s];
        o[O_SA + b * 576 + s] = a;
        o[O_SA + b * 576 + 288 + s] = gnb[s] - mu * a;
    }
}

// ================= dynamic local conv + GN(folded) + BN(b2) + swish + y-GAP ====
__global__ __launch_bounds__(256) void dynconv(
    const bf16* __restrict__ xq, const bf16* __restrict__ wemb,
    const float* __restrict__ fold,
    const float* __restrict__ b2s, const float* __restrict__ b2b,
    bf16* __restrict__ y, float* __restrict__ gap)
{
    int t = threadIdx.x;
    int grp = t & 31, pl = t >> 5;
    int bid = blockIdx.x;                  // 16 b x 392 tiles
    int b = bid / 392;
    int p0 = (bid - b * 392) * 8;
    int p = p0 + pl;
    int h = p / HDIM, w = p - h * HDIM;    // all 8 pixels in one row (8 | 56)

    __shared__ bf16 WE[2304];              // 8 px x 288, contiguous slab
    __shared__ float SAB[576];             // SA[0..288) | SC[288..576)
    __shared__ float R[8][256];

    {
        const bf16* src = wemb + (long)(b * NPIX + p0) * 288;
        #pragma unroll
        for (int i = 0; i < 2; i++) {
            int s = t + i * 256;
            if (s < 288) *(float4*)&WE[s * 8] = *(const float4*)(src + s * 8);
        }
    }
    {
        const float4* src = (const float4*)(fold + O_SA + b * 576);
        if (t < 144) ((float4*)SAB)[t] = src[t];
    }
    __syncthreads();

    // ---- 9 unconditional tap loads from padded xq ----
    long base = ((long)b * PPIX + (h + 1) * 58 + (w + 1)) * 256 + grp * 8;
    const bf16* rm = xq + base - 58 * 256;
    const bf16* rc = xq + base;
    const bf16* rq = xq + base + 58 * 256;
    s16x8 xv[9];
    xv[0] = *(const s16x8*)(rm - 256); xv[1] = *(const s16x8*)rm; xv[2] = *(const s16x8*)(rm + 256);
    xv[3] = *(const s16x8*)(rc - 256); xv[4] = *(const s16x8*)rc; xv[5] = *(const s16x8*)(rc + 256);
    xv[6] = *(const s16x8*)(rq - 256); xv[7] = *(const s16x8*)rq; xv[8] = *(const s16x8*)(rq + 256);

    float acc[8] = {};
    #pragma unroll
    for (int tp = 0; tp < 9; tp++) {
        int wi = grp * 9 + tp;
        float wt = b2f(WE[pl * 288 + wi]) * SAB[wi] + SAB[288 + wi];
        const bf16* xb = (const bf16*)&xv[tp];
        #pragma unroll
        for (int i = 0; i < 8; i++) acc[i] += b2f(xb[i]) * wt;
    }

    bf16 outv[8];
    float sv[8];
    #pragma unroll
    for (int i = 0; i < 8; i++) {
        int c = grp * 8 + i;
        float v = acc[i] * b2s[c] + b2b[c];
        float sw = v / (1.f + __expf(-v));
        sv[i] = sw;
        outv[i] = f2b(sw);
    }
    *(float4*)(y + ((long)b * NPIX + p) * CDIM + grp * 8) = *(const float4*)outv;

    // ---- fused y-GAP: reduce 8 pixels per block in LDS, 1 atomic/thread ----
    #pragma unroll
    for (int i = 0; i < 8; i++) R[pl][grp * 8 + i] = sv[i];
    __syncthreads();
    float s = 0.f;
    #pragma unroll
    for (int j = 0; j < 8; j++) s += R[j][t];
    atomicAdd(&gap[b * 256 + t], s);
}

// ================= split attention ============================================
__global__ void attnk(const float* __restrict__ gap,
                      const float* __restrict__ s1w, const float* __restrict__ s1b,
                      const float* __restrict__ s1s, const float* __restrict__ s1bi,
                      const float* __restrict__ s2w, const float* __restrict__ s2b,
                      float* __restrict__ att)
{
    int b = blockIdx.x, t = threadIdx.x;   // 128 threads
    __shared__ float g[256], a1[128];
    for (int i = t; i < 256; i += 128) g[i] = gap[b * 256 + i] * (1.f / NPIX);
    __syncthreads();
    float s = 0.f;
    for (int ci = 0; ci < 256; ci++) s += s1w[t * 256 + ci] * g[ci];
    s += s1b[t];
    s = s * s1s[t] + s1bi[t];
    a1[t] = fmaxf(s, 0.f);
    __syncthreads();
    for (int c = t; c < 256; c += 128) {
        float v0 = s2b[2 * c], v1 = s2b[2 * c + 1];
        for (int ci = 0; ci < 128; ci++) {
            float av = a1[ci];
            v0 += s2w[(2 * c) * 128 + ci] * av;
            v1 += s2w[(2 * c + 1) * 128 + ci] * av;
        }
        float m = fmaxf(v0, v1);
        float e0 = __expf(v0 - m), e1 = __expf(v1 - m);
        float inv = 1.f / (e0 + e1);
        att[(b * 256 + c) * 2 + 0] = e0 * inv;
        att[(b * 256 + c) * 2 + 1] = e1 * inv;
    }
}

// ================= final: combine + NHWC->NCHW fp32 out =======================
__global__ __launch_bounds__(256) void finalk(
    const bf16* __restrict__ y, const bf16* __restrict__ k,
    const float* __restrict__ att, float* __restrict__ out)
{
    int b = blockIdx.z, c0 = blockIdx.y * 64, p0 = blockIdx.x * 64;
    __shared__ bf16 Ys[64][72], Ks[64][72];
    int t = threadIdx.x;
    #pragma unroll
    for (int i = 0; i < 2; i++) {
        int slot = t + i * 256;
        int row = slot >> 3, cc = slot & 7;
        long off = ((long)b * NPIX + p0 + row) * CDIM + c0 + cc * 8;
        *(float4*)&Ys[row][cc * 8] = *(const float4*)(y + off);
        *(float4*)&Ks[row][cc * 8] = *(const float4*)(k + off);
    }
    __syncthreads();
    int c_l = t >> 2, pc = t & 3;
    int c = c0 + c_l;
    float a0 = att[(b * 256 + c) * 2], a1 = att[(b * 256 + c) * 2 + 1];
    float4 o[4];
    float* of = (float*)o;
    #pragma unroll
    for (int j = 0; j < 16; j++) {
        int p = pc * 16 + j;
        of[j] = b2f(Ys[p][c_l]) * a0 + b2f(Ks[p][c_l]) * a1;
    }
    float* dst = out + ((long)b * CDIM + c) * NPIX + p0 + pc * 16;
    #pragma unroll
    for (int j = 0; j < 4; j++) ((float4*)dst)[j] = o[j];
}

extern "C" void kernel_launch(void* const* d_in, const int* in_sizes, int n_in,
                              void* d_out, int out_size, void* d_ws, size_t ws_size,
                              hipStream_t stream)
{
    const float* x    = (const float*)d_in[0];
    const float* ke_w = (const float*)d_in[1];
    const float* ke_g = (const float*)d_in[2];
    const float* ke_b = (const float*)d_in[3];
    const float* ke_m = (const float*)d_in[4];
    const float* ke_v = (const float*)d_in[5];
    const float* e1_w = (const float*)d_in[6];
    const float* e1_g = (const float*)d_in[7];
    const float* e1_b = (const float*)d_in[8];
    const float* e1_m = (const float*)d_in[9];
    const float* e1_v = (const float*)d_in[10];
    const float* e2_w = (const float*)d_in[11];
    const float* e2_b = (const float*)d_in[12];
    const float* gng  = (const float*)d_in[13];
    const float* gnb  = (const float*)d_in[14];
    const float* c1_w = (const float*)d_in[15];
    const float* c1_g = (const float*)d_in[16];
    const float* c1_b = (const float*)d_in[17];
    const float* c1_m = (const float*)d_in[18];
    const float* c1_v = (const float*)d_in[19];
    const float* b2_g = (const float*)d_in[20];
    const float* b2_b = (const float*)d_in[21];
    const float* b2_m = (const float*)d_in[22];
    const float* b2_v = (const float*)d_in[23];
    const float* s1_w = (const float*)d_in[24];
    const float* s1_b = (const float*)d_in[25];
    const float* s1_g = (const float*)d_in[26];
    const float* s1_bb= (const float*)d_in[27];
    const float* s1_m = (const float*)d_in[28];
    const float* s1_v = (const float*)d_in[29];
    const float* s2_w = (const float*)d_in[30];
    const float* s2_b = (const float*)d_in[31];

    float* fold = (float*)d_ws;           // 128 KB
    bf16* wsb   = (bf16*)((char*)d_ws + 131072);
    bf16* xh   = wsb;                     // padded: 16*3364*256 = 13,778,944
    bf16* kh   = xh + 13778944L;          // 12,845,056
    bf16* wemb = kh + 12845056L;          // 14,450,688
    bf16* w1   = wemb + 14450688L;        // 6,422,528 (e1 out)
    bf16* kewT = w1 + 6422528L;           // 147,456
    bf16* e1wb = kewT + 147456L;          // 65,536
    bf16* e2wb = e1wb + 65536L;           // 36,864
    bf16* c1wb = e2wb + 36864L;           // 65,536
    bf16* xq   = c1wb + 65536L;           // padded: 13,778,944
    bf16* yb   = xh;                      // alias (xh dead after e1; unpadded)

    prep<<<dim3(2165), dim3(256), 0, stream>>>(
        ke_w, e1_w, e2_w, c1_w,
        ke_g, ke_b, ke_m, ke_v, e1_g, e1_b, e1_m, e1_v, e2_b,
        c1_g, c1_b, c1_m, c1_v, b2_g, b2_b, b2_m, b2_v,
        s1_g, s1_bb, s1_m, s1_v,
        kewT, e1wb, e2wb, c1wb, fold, xh, xq);

    cvt_x<<<dim3(49, 4, 16), dim3(256), 0, stream>>>(x, xh);

    gconv_c1<<<dim3(210, 1, 16), dim3(256), 0, stream>>>(
        xh, kewT, fold + O_KE_S, fold + O_KE_B,
        c1wb, fold + O_C1_S, fold + O_C1_B,
        kh, xq, fold + O_GAP);

    mfma_gemm_e1<<<dim3(49, 16), dim3(256), 0, stream>>>(
        e1wb, xh, kh, fold + O_E1_S, fold + O_E1_B, w1);

    mfma_gemm_e2<<<dim3(49, 3, 16), dim3(256), 0, stream>>>(
        e2wb, w1, fold + O_E2B, wemb, fold + O_GNS);

    gnfold<<<dim3(16), dim3(256), 0, stream>>>(fold + O_GNS, gng, gnb, fold);

    dynconv<<<dim3(6272), dim3(256), 0, stream>>>(
        xq, wemb, fold, fold + O_B2_S, fold + O_B2_B, yb, fold + O_GAP);

    attnk<<<dim3(16), dim3(128), 0, stream>>>(
        fold + O_GAP, s1_w, s1_b, fold + O_S1_S, fold + O_S1_B, s2_w, s2_b, fold + O_ATT);

    finalk<<<dim3(49, 4, 16), dim3(256), 0, stream>>>(yb, kh, fold + O_ATT, (float*)d_out);
}

// Round 12
// 326.197 us; speedup vs baseline: 1.1077x; 1.0210x over previous
//
#include <hip/hip_runtime.h>
#include <hip/hip_bf16.h>

typedef __hip_bfloat16 bf16;
typedef float f32x4 __attribute__((ext_vector_type(4)));
typedef short s16x8 __attribute__((ext_vector_type(8)));

#define NPIX 3136   // 56*56
#define HDIM 56
#define CDIM 256
#define PPIX 3364   // 58*58 padded

static __device__ __forceinline__ float b2f(bf16 v){ return __bfloat162float(v); }
static __device__ __forceinline__ bf16  f2b(float v){ return __float2bfloat16(v); }

// ---- fold region float offsets (fold = 128 KB = 32768 floats) ----
#define O_KE_S 0
#define O_KE_B 256
#define O_E1_S 512
#define O_E1_B 640
#define O_C1_S 768
#define O_C1_B 1024
#define O_B2_S 1280
#define O_B2_B 1536
#define O_S1_S 1792
#define O_S1_B 1920
#define O_E2B  2048
#define O_GNS  2336   // gnsum[b][grp][2] : 16*32*2 = 1024 floats
#define O_GAP  3360   // raw sums of (y+k) over pixels, scaled by 1/NPIX in attnk
#define O_ATT  7456   // 16*256*2 = 8192 -> ends 15648
#define O_SA   15872  // SA/SC folded GN affine: [b][576], ends 25088

// ========== preconv: prep (bid<2165) MERGED with cvt_x (bid>=2165) ============
__global__ __launch_bounds__(256) void preconv(
    const float* __restrict__ x,
    const float* __restrict__ kew, const float* __restrict__ e1w,
    const float* __restrict__ e2w, const float* __restrict__ c1w,
    const float* keg, const float* keb, const float* kem, const float* kev,
    const float* e1g, const float* e1b, const float* e1m, const float* e1v,
    const float* e2b,
    const float* c1g, const float* c1b, const float* c1m, const float* c1v,
    const float* b2g, const float* b2b, const float* b2m, const float* b2v,
    const float* s1g, const float* s1bb, const float* s1m, const float* s1v,
    bf16* kewT, bf16* e1wb, bf16* e2wb, bf16* c1wb, float* o,
    bf16* xh, bf16* xq)
{
    int bid = blockIdx.x, t = threadIdx.x;
    __shared__ bf16 T[64][72];
    if (bid >= 2165) {
        // ---------------- cvt_x branch: 64px x 64ch tile ----------------
        int cbid = bid - 2165;             // 0..3135
        int px = cbid % 49;
        int r = cbid / 49;
        int cy = r & 3, b = r >> 2;
        int c0 = cy * 64, p0 = px * 64;
        #pragma unroll
        for (int it = 0; it < 4; it++) {
            int slot = t + it * 256;
            int cl = slot >> 4, ch4 = slot & 15;
            float4 v = *(const float4*)(x + ((long)b * CDIM + c0 + cl) * NPIX + p0 + ch4 * 4);
            T[ch4 * 4 + 0][cl] = f2b(v.x);
            T[ch4 * 4 + 1][cl] = f2b(v.y);
            T[ch4 * 4 + 2][cl] = f2b(v.z);
            T[ch4 * 4 + 3][cl] = f2b(v.w);
        }
        __syncthreads();
        #pragma unroll
        for (int it = 0; it < 2; it++) {
            int slot = t + it * 256;
            int p = slot >> 3, cc = slot & 7;
            int pl = p0 + p;
            int h = pl / HDIM, w = pl - h * HDIM;
            *(float4*)(xh + ((long)b * PPIX + (h + 1) * 58 + (w + 1)) * 256 + c0 + cc * 8) = *(const float4*)&T[p][cc * 8];
        }
        return;
    }
    // ---------------- prep branch ----------------
    if (bid < 576) {                       // kewT: (256,64,3,3) -> [g][tap][co_l][ci]
        int i = bid * 256 + t;
        int ci = i & 63, co_l = (i >> 6) & 63;
        int gt = i >> 12;
        int tap = gt % 9, g = gt / 9;
        int co = g * 64 + co_l;
        kewT[i] = f2b(kew[(co * 64 + ci) * 9 + tap]);
    } else if (bid < 832) {
        int i = (bid - 576) * 256 + t; e1wb[i] = f2b(e1w[i]);
    } else if (bid < 976) {
        int i = (bid - 832) * 256 + t; e2wb[i] = f2b(e2w[i]);
    } else if (bid < 1232) {
        int i = (bid - 976) * 256 + t; c1wb[i] = f2b(c1w[i]);
    } else if (bid == 1232) {
        const float eps = 1e-5f;
        {
            float s = keg[t] * rsqrtf(kev[t] + eps);
            o[O_KE_S + t] = s; o[O_KE_B + t] = keb[t] - kem[t] * s;
            s = c1g[t] * rsqrtf(c1v[t] + eps);
            o[O_C1_S + t] = s; o[O_C1_B + t] = c1b[t] - c1m[t] * s;
            s = b2g[t] * rsqrtf(b2v[t] + eps);
            o[O_B2_S + t] = s; o[O_B2_B + t] = b2b[t] - b2m[t] * s;
        }
        if (t < 128) {
            float s = e1g[t] * rsqrtf(e1v[t] + eps);
            o[O_E1_S + t] = s; o[O_E1_B + t] = e1b[t] - e1m[t] * s;
            s = s1g[t] * rsqrtf(s1v[t] + eps);
            o[O_S1_S + t] = s; o[O_S1_B + t] = s1bb[t] - s1m[t] * s;
        }
        for (int i = t; i < 288; i += 256) o[O_E2B + i] = e2b[i];
    } else if (bid < 1253) {                // zeros: gnsum (1024) + gap (4096)
        int j = (bid - 1233) * 256 + t;
        if (j < 1024) o[O_GNS + j] = 0.f;
        else if (j < 5120) o[O_GAP + j - 1024] = 0.f;
    } else {                                // pad borders of xh and xq (zero)
        int j = (bid - 1253) * 256 + t;     // 0 .. 233471 = 2*16*7296
        bf16* arr = (j >= 116736) ? xq : xh;
        int r = j % 116736;
        int img = r / 7296;
        int s = r % 7296;
        int pi = s >> 5, cc = s & 31;
        int pos;
        if (pi < 58)       pos = pi;                     // top row
        else if (pi < 116) pos = 57 * 58 + (pi - 58);    // bottom row
        else if (pi < 172) pos = (pi - 115) * 58;        // left col rows 1..56
        else               pos = (pi - 171) * 58 + 57;   // right col rows 1..56
        float4 z = {0.f, 0.f, 0.f, 0.f};
        *(float4*)(arr + ((long)img * PPIX + pos) * 256 + cc * 8) = z;
    }
}

// ================= MERGED: grouped 3x3 conv  ||  c1 1x1 GEMM ===================
// grid (210, 1, 16): bx<112 -> gconv (tile=bx>>2, group=bx&3);
//                    bx>=112 -> c1 (mt=(bx-112)&1, px=(bx-112)>>1).
__global__ __launch_bounds__(256) void gconv_c1(
    const bf16* __restrict__ xp, const bf16* __restrict__ wT,
    const float* __restrict__ kes, const float* __restrict__ keb,
    const bf16* __restrict__ c1w,
    const float* __restrict__ c1s, const float* __restrict__ c1b,
    bf16* __restrict__ kh, bf16* __restrict__ xq, float* __restrict__ gap)
{
    __shared__ bf16 SH[232 * 64];          // 14848 elems; both branches fit
    int b = blockIdx.z;
    int bx = blockIdx.x;
    int t = threadIdx.x;
    int wv = t >> 6, lane = t & 63, q = lane >> 4, ln = lane & 15;

    if (bx < 112) {
        // ---------------- gconv branch ----------------
        int hx = bx >> 2, g = bx & 3;
        int h0 = hx * 2;
        bf16* As = SH;
        #pragma unroll
        for (int i = 0; i < 8; i++) {
            int slot = t + i * 256;
            if (slot < 1856) {
                int pos = slot >> 3, chunkL = slot & 7;
                int ri = pos / 58, ci = pos - ri * 58;
                int chunkg = chunkL ^ (pos & 7);
                float4 v = *(const float4*)(xp + (((long)b * PPIX + (h0 + ri) * 58 + ci) * 256 + g * 64 + chunkg * 8));
                *(float4*)&SH[pos * 64 + chunkL * 8] = v;
            }
        }
        int posb[7];
        #pragma unroll
        for (int pt = 0; pt < 7; pt++) {
            int p = pt * 16 + ln;
            int prow = (p >= 56) ? 1 : 0;
            int pcol = p - prow * 56;
            posb[pt] = prow * 58 + pcol + 1;
        }
        const bf16* wbase = wT + ((long)(g * 9) * 64 + wv * 16 + ln) * 64;
        __syncthreads();

        f32x4 acc[7] = {};
        #pragma unroll
        for (int tap = 0; tap < 9; tap++) {
            const int dr = tap / 3;
            const int dc = tap % 3 - 1;
            const bf16* wq = wbase + tap * 64 * 64;
            s16x8 B0 = *(const s16x8*)(wq + q * 8);
            s16x8 B1 = *(const s16x8*)(wq + 32 + q * 8);
            #pragma unroll
            for (int pt = 0; pt < 7; pt++) {
                int pos = posb[pt] + dr * 58 + dc;
                int off0 = pos * 64 + ((q ^ (pos & 7)) * 8);
                s16x8 a0 = *(const s16x8*)&As[off0];
                s16x8 a1 = *(const s16x8*)&As[off0 ^ 32];
                acc[pt] = __builtin_amdgcn_mfma_f32_16x16x32_bf16(a0, B0, acc[pt], 0, 0, 0);
                acc[pt] = __builtin_amdgcn_mfma_f32_16x16x32_bf16(a1, B1, acc[pt], 0, 0, 0);
            }
        }
        __syncthreads();
        bf16* T = As;                      // 112 x 72
        int co = g * 64 + wv * 16 + ln;
        float sc = kes[co], bi = keb[co];
        #pragma unroll
        for (int pt = 0; pt < 7; pt++)
            #pragma unroll
            for (int r = 0; r < 4; r++)
                T[(pt * 16 + q * 4 + r) * 72 + wv * 16 + ln] = f2b(fmaxf(acc[pt][r] * sc + bi, 0.f));
        __syncthreads();
        int pimg0 = hx * 112;
        #pragma unroll
        for (int i = 0; i < 4; i++) {
            int slot = t + i * 256;
            if (slot < 896) {
                int row = slot >> 3, cc = slot & 7;
                *(float4*)(kh + ((long)b * NPIX + pimg0 + row) * CDIM + g * 64 + cc * 8) = *(const float4*)&T[row * 72 + cc * 8];
            }
        }
        {
            int co_l = t & 63, rb = t >> 6;
            float s = 0.f;
            #pragma unroll
            for (int r = 0; r < 28; r++) s += b2f(T[(rb * 28 + r) * 72 + co_l]);
            atomicAdd(&gap[b * 256 + g * 64 + co_l], s);
        }
    } else {
        // ---------------- c1 branch (K=256, M=256, padded out) ----------------
        int px = bx - 112;
        int mt = px & 1; px >>= 1;         // px in [0,49)
        int p0 = px * 64;
        int m0 = mt * 128;
        bf16* As = SH;                     // 64 x 72
        bf16* Bs = SH + 64 * 72;           // 128 x 72

        f32x4 acc[4][2] = {};
        for (int k0 = 0; k0 < 256; k0 += 64) {
            __syncthreads();
            #pragma unroll
            for (int i = 0; i < 2; i++) {
                int slot = t + i * 256;
                int chunk = slot & 7, row = slot >> 3;
                long pp = p0 + row;
                long pidx = (long)b * PPIX + pp + 2 * (pp / HDIM) + 59;
                *(float4*)&As[row * 72 + chunk * 8] = *(const float4*)(xp + pidx * 256 + k0 + chunk * 8);
            }
            #pragma unroll
            for (int i = 0; i < 4; i++) {
                int slot = t + i * 256;
                int chunk = slot & 7, row = slot >> 3;
                *(float4*)&Bs[row * 72 + chunk * 8] = *(const float4*)(c1w + (long)(m0 + row) * 256 + k0 + chunk * 8);
            }
            __syncthreads();
            #pragma unroll
            for (int kk = 0; kk < 2; kk++) {
                s16x8 a[4];
                #pragma unroll
                for (int pt = 0; pt < 4; pt++)
                    a[pt] = *(const s16x8*)&As[(pt * 16 + ln) * 72 + kk * 32 + q * 8];
                #pragma unroll
                for (int mi = 0; mi < 2; mi++) {
                    s16x8 bb = *(const s16x8*)&Bs[(wv * 32 + mi * 16 + ln) * 72 + kk * 32 + q * 8];
                    #pragma unroll
                    for (int pt = 0; pt < 4; pt++)
                        acc[pt][mi] = __builtin_amdgcn_mfma_f32_16x16x32_bf16(a[pt], bb, acc[pt][mi], 0, 0, 0);
                }
            }
        }
        __syncthreads();
        bf16* T = SH;                      // 64 x 144
        #pragma unroll
        for (int mi = 0; mi < 2; mi++) {
            int m = m0 + wv * 32 + mi * 16 + ln;
            float sc = c1s[m], bi = c1b[m];
            #pragma unroll
            for (int pt = 0; pt < 4; pt++) {
                #pragma unroll
                for (int r = 0; r < 4; r++) {
                    float v = acc[pt][mi][r] * sc + bi;
                    T[(pt * 16 + q * 4 + r) * 144 + wv * 32 + mi * 16 + ln] = f2b(v);
                }
            }
        }
        __syncthreads();
        #pragma unroll
        for (int i = 0; i < 4; i++) {
            int slot = t + i * 256;
            int row = slot >> 4, chunk = slot & 15;
            long pp = p0 + row;
            long pidx = (long)b * PPIX + pp + 2 * (pp / HDIM) + 59;
            *(float4*)(xq + pidx * 256 + m0 + chunk * 8) = *(const float4*)&T[row * 144 + chunk * 8];
        }
    }
}

// ================= e1 1x1-conv GEMM (K=512: xh | kh, M=128, ReLU) ==============
// grid (49, 16), block 256 (4 waves)
__global__ __launch_bounds__(256) void mfma_gemm_e1(
    const bf16* __restrict__ Wt, const bf16* __restrict__ X0, const bf16* __restrict__ X1,
    const float* __restrict__ scale, const float* __restrict__ bias,
    bf16* __restrict__ Y)
{
    int b = blockIdx.y;
    int p0 = blockIdx.x * 64;
    __shared__ bf16 SH[64 * 72 + 128 * 72];
    bf16* As = SH;
    bf16* Bs = SH + 64 * 72;
    int t = threadIdx.x;
    int wv = t >> 6, lane = t & 63, q = lane >> 4, ln = lane & 15;

    f32x4 acc[4][2] = {};
    for (int k0 = 0; k0 < 512; k0 += 64) {
        __syncthreads();
        #pragma unroll
        for (int i = 0; i < 2; i++) {
            int slot = t + i * 256;
            int chunk = slot & 7, row = slot >> 3;
            int ch = k0 + chunk * 8;
            const bf16* src;
            if (ch < 256) {
                long pp = p0 + row;
                long pidx = (long)b * PPIX + pp + 2 * (pp / HDIM) + 59;
                src = X0 + pidx * 256 + ch;
            } else {
                src = X1 + ((long)b * NPIX + p0 + row) * 256 + (ch - 256);
            }
            *(float4*)&As[row * 72 + chunk * 8] = *(const float4*)src;
        }
        #pragma unroll
        for (int i = 0; i < 4; i++) {
            int slot = t + i * 256;
            int chunk = slot & 7, row = slot >> 3;
            *(float4*)&Bs[row * 72 + chunk * 8] = *(const float4*)(Wt + (long)row * 512 + k0 + chunk * 8);
        }
        __syncthreads();
        #pragma unroll
        for (int kk = 0; kk < 2; kk++) {
            s16x8 a[4];
            #pragma unroll
            for (int pt = 0; pt < 4; pt++)
                a[pt] = *(const s16x8*)&As[(pt * 16 + ln) * 72 + kk * 32 + q * 8];
            #pragma unroll
            for (int mi = 0; mi < 2; mi++) {
                s16x8 bb = *(const s16x8*)&Bs[(wv * 32 + mi * 16 + ln) * 72 + kk * 32 + q * 8];
                #pragma unroll
                for (int pt = 0; pt < 4; pt++)
                    acc[pt][mi] = __builtin_amdgcn_mfma_f32_16x16x32_bf16(a[pt], bb, acc[pt][mi], 0, 0, 0);
            }
        }
    }
    __syncthreads();
    bf16* T = SH;                     // 64 x 144
    #pragma unroll
    for (int mi = 0; mi < 2; mi++) {
        int m = wv * 32 + mi * 16 + ln;
        float sc = scale[m], bi = bias[m];
        #pragma unroll
        for (int pt = 0; pt < 4; pt++) {
            #pragma unroll
            for (int r = 0; r < 4; r++) {
                float v = fmaxf(acc[pt][mi][r] * sc + bi, 0.f);
                T[(pt * 16 + q * 4 + r) * 144 + m] = f2b(v);
            }
        }
    }
    __syncthreads();
    #pragma unroll
    for (int i = 0; i < 4; i++) {
        int slot = t + i * 256;
        int row = slot >> 4, chunk = slot & 15;
        *(float4*)(Y + ((long)b * NPIX + p0 + row) * 128 + chunk * 8) = *(const float4*)&T[row * 144 + chunk * 8];
    }
}

// ================= 1x1 conv GEMM (e2): +bias + fused GN partial sums ===========
// grid (49, 3, 16), block 256 (4 waves)
__global__ __launch_bounds__(256) void mfma_gemm_e2(
    const bf16* __restrict__ Wt, const bf16* __restrict__ X0,
    const float* __restrict__ bias,
    bf16* __restrict__ Y, float* __restrict__ gnsum)
{
    const int K = 128, M = 288;
    int b = blockIdx.z;
    int p0 = blockIdx.x * 64;
    int m0 = blockIdx.y * 128;
    __shared__ bf16 SH[64 * 72 + 128 * 72];
    bf16* As = SH;
    bf16* Bs = SH + 64 * 72;
    __shared__ float gs[64];
    int t = threadIdx.x;
    int wv = t >> 6, lane = t & 63, q = lane >> 4, ln = lane & 15;
    if (t < 64) gs[t] = 0.f;

    f32x4 acc[4][2] = {};
    for (int k0 = 0; k0 < K; k0 += 64) {
        __syncthreads();
        #pragma unroll
        for (int i = 0; i < 2; i++) {
            int slot = t + i * 256;
            int chunk = slot & 7, row = slot >> 3;
            int ch = k0 + chunk * 8;
            *(float4*)&As[row * 72 + chunk * 8] = *(const float4*)(X0 + ((long)b * NPIX + p0 + row) * K + ch);
        }
        #pragma unroll
        for (int i = 0; i < 4; i++) {
            int slot = t + i * 256;
            int chunk = slot & 7, row = slot >> 3;
            int m = m0 + row;
            float4 v = {0.f, 0.f, 0.f, 0.f};
            if (m < M) v = *(const float4*)(Wt + (long)m * K + k0 + chunk * 8);
            *(float4*)&Bs[row * 72 + chunk * 8] = v;
        }
        __syncthreads();
        #pragma unroll
        for (int kk = 0; kk < 2; kk++) {
            s16x8 a[4];
            #pragma unroll
            for (int pt = 0; pt < 4; pt++)
                a[pt] = *(const s16x8*)&As[(pt * 16 + ln) * 72 + kk * 32 + q * 8];
            #pragma unroll
            for (int mi = 0; mi < 2; mi++) {
                s16x8 bb = *(const s16x8*)&Bs[(wv * 32 + mi * 16 + ln) * 72 + kk * 32 + q * 8];
                #pragma unroll
                for (int pt = 0; pt < 4; pt++)
                    acc[pt][mi] = __builtin_amdgcn_mfma_f32_16x16x32_bf16(a[pt], bb, acc[pt][mi], 0, 0, 0);
            }
        }
    }

    __syncthreads();
    bf16* T = SH;
    #pragma unroll
    for (int mi = 0; mi < 2; mi++) {
        int m = m0 + wv * 32 + mi * 16 + ln;
        int mc = (m > M - 1) ? (M - 1) : m;
        float bi = bias[mc];
        float ps = 0.f, pq = 0.f;
        #pragma unroll
        for (int pt = 0; pt < 4; pt++) {
            #pragma unroll
            for (int r = 0; r < 4; r++) {
                float v = acc[pt][mi][r] + bi;
                ps += v; pq += v * v;
                T[(pt * 16 + q * 4 + r) * 144 + wv * 32 + mi * 16 + ln] = f2b(v);
            }
        }
        if (m < M) {
            int grp = m / 9;
            atomicAdd(&gs[grp * 2], ps);
            atomicAdd(&gs[grp * 2 + 1], pq);
        }
    }
    __syncthreads();
    #pragma unroll
    for (int i = 0; i < 4; i++) {
        int slot = t + i * 256;
        int chunk = slot & 15, row = slot >> 4;
        int m = m0 + chunk * 8;
        if (m + 8 <= M)
            *(float4*)(Y + ((long)b * NPIX + p0 + row) * M + m) = *(const float4*)&T[row * 144 + chunk * 8];
    }
    if (t < 64) atomicAdd(&gnsum[b * 64 + t], gs[t]);
}

// ================= gnfold: GN affine folds, once per (b, grp, tap) =============
__global__ void gnfold(const float* __restrict__ gnsum,
                       const float* __restrict__ gng, const float* __restrict__ gnb,
                       float* __restrict__ o)
{
    int b = blockIdx.x, t = threadIdx.x;
    for (int s = t; s < 288; s += 256) {
        int g2 = s / 9;
        float S = gnsum[b * 64 + g2 * 2], Q = gnsum[b * 64 + g2 * 2 + 1];
        float mu = S * (1.f / 28224.f);
        float var = Q * (1.f / 28224.f) - mu * mu;
        float rs = rsqrtf(fmaxf(var, 0.f) + 1e-5f);
        float a = rs * gng[s];
        o[O_SA + b * 576 + s] = a;
        o[O_SA + b * 576 + 288 + s] = gnb[s] - mu * a;
    }
}

// ================= dynamic local conv + GN(folded) + BN(b2) + swish + y-GAP ====
__global__ __launch_bounds__(256) void dynconv(
    const bf16* __restrict__ xq, const bf16* __restrict__ wemb,
    const float* __restrict__ fold,
    const float* __restrict__ b2s, const float* __restrict__ b2b,
    bf16* __restrict__ y, float* __restrict__ gap)
{
    int t = threadIdx.x;
    int grp = t & 31, pl = t >> 5;
    int bid = blockIdx.x;                  // 16 b x 392 tiles
    int b = bid / 392;
    int p0 = (bid - b * 392) * 8;
    int p = p0 + pl;
    int h = p / HDIM, w = p - h * HDIM;    // all 8 pixels in one row (8 | 56)

    __shared__ bf16 WE[2304];              // 8 px x 288, contiguous slab
    __shared__ float SAB[576];             // SA[0..288) | SC[288..576)
    __shared__ float R[8][256];

    {
        const bf16* src = wemb + (long)(b * NPIX + p0) * 288;
        #pragma unroll
        for (int i = 0; i < 2; i++) {
            int s = t + i * 256;
            if (s < 288) *(float4*)&WE[s * 8] = *(const float4*)(src + s * 8);
        }
    }
    {
        const float4* src = (const float4*)(fold + O_SA + b * 576);
        if (t < 144) ((float4*)SAB)[t] = src[t];
    }
    __syncthreads();

    // ---- 9 unconditional tap loads from padded xq ----
    long base = ((long)b * PPIX + (h + 1) * 58 + (w + 1)) * 256 + grp * 8;
    const bf16* rm = xq + base - 58 * 256;
    const bf16* rc = xq + base;
    const bf16* rq = xq + base + 58 * 256;
    s16x8 xv[9];
    xv[0] = *(const s16x8*)(rm - 256); xv[1] = *(const s16x8*)rm; xv[2] = *(const s16x8*)(rm + 256);
    xv[3] = *(const s16x8*)(rc - 256); xv[4] = *(const s16x8*)rc; xv[5] = *(const s16x8*)(rc + 256);
    xv[6] = *(const s16x8*)(rq - 256); xv[7] = *(const s16x8*)rq; xv[8] = *(const s16x8*)(rq + 256);

    float acc[8] = {};
    #pragma unroll
    for (int tp = 0; tp < 9; tp++) {
        int wi = grp * 9 + tp;
        float wt = b2f(WE[pl * 288 + wi]) * SAB[wi] + SAB[288 + wi];
        const bf16* xb = (const bf16*)&xv[tp];
        #pragma unroll
        for (int i = 0; i < 8; i++) acc[i] += b2f(xb[i]) * wt;
    }

    bf16 outv[8];
    float sv[8];
    #pragma unroll
    for (int i = 0; i < 8; i++) {
        int c = grp * 8 + i;
        float v = acc[i] * b2s[c] + b2b[c];
        float sw = v / (1.f + __expf(-v));
        sv[i] = sw;
        outv[i] = f2b(sw);
    }
    *(float4*)(y + ((long)b * NPIX + p) * CDIM + grp * 8) = *(const float4*)outv;

    // ---- fused y-GAP: reduce 8 pixels per block in LDS, 1 atomic/thread ----
    #pragma unroll
    for (int i = 0; i < 8; i++) R[pl][grp * 8 + i] = sv[i];
    __syncthreads();
    float s = 0.f;
    #pragma unroll
    for (int j = 0; j < 8; j++) s += R[j][t];
    atomicAdd(&gap[b * 256 + t], s);
}

// ================= split attention ============================================
__global__ void attnk(const float* __restrict__ gap,
                      const float* __restrict__ s1w, const float* __restrict__ s1b,
                      const float* __restrict__ s1s, const float* __restrict__ s1bi,
                      const float* __restrict__ s2w, const float* __restrict__ s2b,
                      float* __restrict__ att)
{
    int b = blockIdx.x, t = threadIdx.x;   // 128 threads
    __shared__ float g[256], a1[128];
    for (int i = t; i < 256; i += 128) g[i] = gap[b * 256 + i] * (1.f / NPIX);
    __syncthreads();
    float s = 0.f;
    for (int ci = 0; ci < 256; ci++) s += s1w[t * 256 + ci] * g[ci];
    s += s1b[t];
    s = s * s1s[t] + s1bi[t];
    a1[t] = fmaxf(s, 0.f);
    __syncthreads();
    for (int c = t; c < 256; c += 128) {
        float v0 = s2b[2 * c], v1 = s2b[2 * c + 1];
        for (int ci = 0; ci < 128; ci++) {
            float av = a1[ci];
            v0 += s2w[(2 * c) * 128 + ci] * av;
            v1 += s2w[(2 * c + 1) * 128 + ci] * av;
        }
        float m = fmaxf(v0, v1);
        float e0 = __expf(v0 - m), e1 = __expf(v1 - m);
        float inv = 1.f / (e0 + e1);
        att[(b * 256 + c) * 2 + 0] = e0 * inv;
        att[(b * 256 + c) * 2 + 1] = e1 * inv;
    }
}

// ================= final: combine + NHWC->NCHW fp32 out =======================
__global__ __launch_bounds__(256) void finalk(
    const bf16* __restrict__ y, const bf16* __restrict__ k,
    const float* __restrict__ att, float* __restrict__ out)
{
    int b = blockIdx.z, c0 = blockIdx.y * 64, p0 = blockIdx.x * 64;
    __shared__ bf16 Ys[64][72], Ks[64][72];
    int t = threadIdx.x;
    #pragma unroll
    for (int i = 0; i < 2; i++) {
        int slot = t + i * 256;
        int row = slot >> 3, cc = slot & 7;
        long off = ((long)b * NPIX + p0 + row) * CDIM + c0 + cc * 8;
        *(float4*)&Ys[row][cc * 8] = *(const float4*)(y + off);
        *(float4*)&Ks[row][cc * 8] = *(const float4*)(k + off);
    }
    __syncthreads();
    int c_l = t >> 2, pc = t & 3;
    int c = c0 + c_l;
    float a0 = att[(b * 256 + c) * 2], a1 = att[(b * 256 + c) * 2 + 1];
    float4 o[4];
    float* of = (float*)o;
    #pragma unroll
    for (int j = 0; j < 16; j++) {
        int p = pc * 16 + j;
        of[j] = b2f(Ys[p][c_l]) * a0 + b2f(Ks[p][c_l]) * a1;
    }
    float* dst = out + ((long)b * CDIM + c) * NPIX + p0 + pc * 16;
    #pragma unroll
    for (int j = 0; j < 4; j++) ((float4*)dst)[j] = o[j];
}

extern "C" void kernel_launch(void* const* d_in, const int* in_sizes, int n_in,
                              void* d_out, int out_size, void* d_ws, size_t ws_size,
                              hipStream_t stream)
{
    const float* x    = (const float*)d_in[0];
    const float* ke_w = (const float*)d_in[1];
    const float* ke_g = (const float*)d_in[2];
    const float* ke_b = (const float*)d_in[3];
    const float* ke_m = (const float*)d_in[4];
    const float* ke_v = (const float*)d_in[5];
    const float* e1_w = (const float*)d_in[6];
    const float* e1_g = (const float*)d_in[7];
    const float* e1_b = (const float*)d_in[8];
    const float* e1_m = (const float*)d_in[9];
    const float* e1_v = (const float*)d_in[10];
    const float* e2_w = (const float*)d_in[11];
    const float* e2_b = (const float*)d_in[12];
    const float* gng  = (const float*)d_in[13];
    const float* gnb  = (const float*)d_in[14];
    const float* c1_w = (const float*)d_in[15];
    const float* c1_g = (const float*)d_in[16];
    const float* c1_b = (const float*)d_in[17];
    const float* c1_m = (const float*)d_in[18];
    const float* c1_v = (const float*)d_in[19];
    const float* b2_g = (const float*)d_in[20];
    const float* b2_b = (const float*)d_in[21];
    const float* b2_m = (const float*)d_in[22];
    const float* b2_v = (const float*)d_in[23];
    const float* s1_w = (const float*)d_in[24];
    const float* s1_b = (const float*)d_in[25];
    const float* s1_g = (const float*)d_in[26];
    const float* s1_bb= (const float*)d_in[27];
    const float* s1_m = (const float*)d_in[28];
    const float* s1_v = (const float*)d_in[29];
    const float* s2_w = (const float*)d_in[30];
    const float* s2_b = (const float*)d_in[31];

    float* fold = (float*)d_ws;           // 128 KB
    bf16* wsb   = (bf16*)((char*)d_ws + 131072);
    bf16* xh   = wsb;                     // padded: 16*3364*256 = 13,778,944
    bf16* kh   = xh + 13778944L;          // 12,845,056
    bf16* wemb = kh + 12845056L;          // 14,450,688
    bf16* w1   = wemb + 14450688L;        // 6,422,528 (e1 out)
    bf16* kewT = w1 + 6422528L;           // 147,456
    bf16* e1wb = kewT + 147456L;          // 65,536
    bf16* e2wb = e1wb + 65536L;           // 36,864
    bf16* c1wb = e2wb + 36864L;           // 65,536
    bf16* xq   = c1wb + 65536L;           // padded: 13,778,944
    bf16* yb   = xh;                      // alias (xh dead after e1; unpadded)

    preconv<<<dim3(5301), dim3(256), 0, stream>>>(
        x, ke_w, e1_w, e2_w, c1_w,
        ke_g, ke_b, ke_m, ke_v, e1_g, e1_b, e1_m, e1_v, e2_b,
        c1_g, c1_b, c1_m, c1_v, b2_g, b2_b, b2_m, b2_v,
        s1_g, s1_bb, s1_m, s1_v,
        kewT, e1wb, e2wb, c1wb, fold, xh, xq);

    gconv_c1<<<dim3(210, 1, 16), dim3(256), 0, stream>>>(
        xh, kewT, fold + O_KE_S, fold + O_KE_B,
        c1wb, fold + O_C1_S, fold + O_C1_B,
        kh, xq, fold + O_GAP);

    mfma_gemm_e1<<<dim3(49, 16), dim3(256), 0, stream>>>(
        e1wb, xh, kh, fold + O_E1_S, fold + O_E1_B, w1);

    mfma_gemm_e2<<<dim3(49, 3, 16), dim3(256), 0, stream>>>(
        e2wb, w1, fold + O_E2B, wemb, fold + O_GNS);

    gnfold<<<dim3(16), dim3(256), 0, stream>>>(fold + O_GNS, gng, gnb, fold);

    dynconv<<<dim3(6272), dim3(256), 0, stream>>>(
        xq, wemb, fold, fold + O_B2_S, fold + O_B2_B, yb, fold + O_GAP);

    attnk<<<dim3(16), dim3(128), 0, stream>>>(
        fold + O_GAP, s1_w, s1_b, fold + O_S1_S, fold + O_S1_B, s2_w, s2_b, fold + O_ATT);

    finalk<<<dim3(49, 4, 16), dim3(256), 0, stream>>>(yb, kh, fold + O_ATT, (float*)d_out);
}

// Round 13
// 325.017 us; speedup vs baseline: 1.1117x; 1.0036x over previous
//
#include <hip/hip_runtime.h>
#include <hip/hip_bf16.h>

typedef __hip_bfloat16 bf16;
typedef float f32x4 __attribute__((ext_vector_type(4)));
typedef short s16x8 __attribute__((ext_vector_type(8)));

#define NPIX 3136   // 56*56
#define HDIM 56
#define CDIM 256
#define PPIX 3364   // 58*58 padded

static __device__ __forceinline__ float b2f(bf16 v){ return __bfloat162float(v); }
static __device__ __forceinline__ bf16  f2b(float v){ return __float2bfloat16(v); }

// ---- fold region float offsets (fold = 128 KB = 32768 floats) ----
#define O_KE_S 0
#define O_KE_B 256
#define O_E1_S 512
#define O_E1_B 640
#define O_C1_S 768
#define O_C1_B 1024
#define O_B2_S 1280
#define O_B2_B 1536
#define O_S1_S 1792
#define O_S1_B 1920
#define O_E2B  2048
#define O_GNS  2336   // gnsum[b][grp][2] : 16*32*2 = 1024 floats
#define O_GAP  3360   // raw sums of (y+k) over pixels, scaled by 1/NPIX in attnk
#define O_ATT  7456   // 16*256*2 = 8192 -> ends 15648
#define O_SA   15872  // SA/SC folded GN affine: [b][576], ends 25088

// ========== preconv: prep (bid<2165) MERGED with cvt_x (bid>=2165) ============
__global__ __launch_bounds__(256) void preconv(
    const float* __restrict__ x,
    const float* __restrict__ kew, const float* __restrict__ e1w,
    const float* __restrict__ e2w, const float* __restrict__ c1w,
    const float* keg, const float* keb, const float* kem, const float* kev,
    const float* e1g, const float* e1b, const float* e1m, const float* e1v,
    const float* e2b,
    const float* c1g, const float* c1b, const float* c1m, const float* c1v,
    const float* b2g, const float* b2b, const float* b2m, const float* b2v,
    const float* s1g, const float* s1bb, const float* s1m, const float* s1v,
    bf16* kewT, bf16* e1wb, bf16* e2wb, bf16* c1wb, float* o,
    bf16* xh, bf16* xq)
{
    int bid = blockIdx.x, t = threadIdx.x;
    __shared__ bf16 T[64][72];
    if (bid >= 2165) {
        // ---------------- cvt_x branch: 64px x 64ch tile ----------------
        int cbid = bid - 2165;             // 0..3135
        int px = cbid % 49;
        int r = cbid / 49;
        int cy = r & 3, b = r >> 2;
        int c0 = cy * 64, p0 = px * 64;
        #pragma unroll
        for (int it = 0; it < 4; it++) {
            int slot = t + it * 256;
            int cl = slot >> 4, ch4 = slot & 15;
            float4 v = *(const float4*)(x + ((long)b * CDIM + c0 + cl) * NPIX + p0 + ch4 * 4);
            T[ch4 * 4 + 0][cl] = f2b(v.x);
            T[ch4 * 4 + 1][cl] = f2b(v.y);
            T[ch4 * 4 + 2][cl] = f2b(v.z);
            T[ch4 * 4 + 3][cl] = f2b(v.w);
        }
        __syncthreads();
        #pragma unroll
        for (int it = 0; it < 2; it++) {
            int slot = t + it * 256;
            int p = slot >> 3, cc = slot & 7;
            int pl = p0 + p;
            int h = pl / HDIM, w = pl - h * HDIM;
            *(float4*)(xh + ((long)b * PPIX + (h + 1) * 58 + (w + 1)) * 256 + c0 + cc * 8) = *(const float4*)&T[p][cc * 8];
        }
        return;
    }
    // ---------------- prep branch ----------------
    if (bid < 576) {                       // kewT: (256,64,3,3) -> [g][tap][co_l][ci]
        int i = bid * 256 + t;
        int ci = i & 63, co_l = (i >> 6) & 63;
        int gt = i >> 12;
        int tap = gt % 9, g = gt / 9;
        int co = g * 64 + co_l;
        kewT[i] = f2b(kew[(co * 64 + ci) * 9 + tap]);
    } else if (bid < 832) {
        int i = (bid - 576) * 256 + t; e1wb[i] = f2b(e1w[i]);
    } else if (bid < 976) {
        int i = (bid - 832) * 256 + t; e2wb[i] = f2b(e2w[i]);
    } else if (bid < 1232) {
        int i = (bid - 976) * 256 + t; c1wb[i] = f2b(c1w[i]);
    } else if (bid == 1232) {
        const float eps = 1e-5f;
        {
            float s = keg[t] * rsqrtf(kev[t] + eps);
            o[O_KE_S + t] = s; o[O_KE_B + t] = keb[t] - kem[t] * s;
            s = c1g[t] * rsqrtf(c1v[t] + eps);
            o[O_C1_S + t] = s; o[O_C1_B + t] = c1b[t] - c1m[t] * s;
            s = b2g[t] * rsqrtf(b2v[t] + eps);
            o[O_B2_S + t] = s; o[O_B2_B + t] = b2b[t] - b2m[t] * s;
        }
        if (t < 128) {
            float s = e1g[t] * rsqrtf(e1v[t] + eps);
            o[O_E1_S + t] = s; o[O_E1_B + t] = e1b[t] - e1m[t] * s;
            s = s1g[t] * rsqrtf(s1v[t] + eps);
            o[O_S1_S + t] = s; o[O_S1_B + t] = s1bb[t] - s1m[t] * s;
        }
        for (int i = t; i < 288; i += 256) o[O_E2B + i] = e2b[i];
    } else if (bid < 1253) {                // zeros: gnsum (1024) + gap (4096)
        int j = (bid - 1233) * 256 + t;
        if (j < 1024) o[O_GNS + j] = 0.f;
        else if (j < 5120) o[O_GAP + j - 1024] = 0.f;
    } else {                                // pad borders of xh and xq (zero)
        int j = (bid - 1253) * 256 + t;     // 0 .. 233471 = 2*16*7296
        bf16* arr = (j >= 116736) ? xq : xh;
        int r = j % 116736;
        int img = r / 7296;
        int s = r % 7296;
        int pi = s >> 5, cc = s & 31;
        int pos;
        if (pi < 58)       pos = pi;                     // top row
        else if (pi < 116) pos = 57 * 58 + (pi - 58);    // bottom row
        else if (pi < 172) pos = (pi - 115) * 58;        // left col rows 1..56
        else               pos = (pi - 171) * 58 + 57;   // right col rows 1..56
        float4 z = {0.f, 0.f, 0.f, 0.f};
        *(float4*)(arr + ((long)img * PPIX + pos) * 256 + cc * 8) = z;
    }
}

// ================= MERGED: grouped 3x3 conv  ||  c1 1x1 GEMM ===================
// grid (210, 1, 16): bx<112 -> gconv (tile=bx>>2, group=bx&3);
//                    bx>=112 -> c1 (mt=(bx-112)&1, px=(bx-112)>>1).
__global__ __launch_bounds__(256) void gconv_c1(
    const bf16* __restrict__ xp, const bf16* __restrict__ wT,
    const float* __restrict__ kes, const float* __restrict__ keb,
    const bf16* __restrict__ c1w,
    const float* __restrict__ c1s, const float* __restrict__ c1b,
    bf16* __restrict__ kh, bf16* __restrict__ xq, float* __restrict__ gap)
{
    __shared__ bf16 SH[232 * 64];          // 14848 elems; both branches fit
    int b = blockIdx.z;
    int bx = blockIdx.x;
    int t = threadIdx.x;
    int wv = t >> 6, lane = t & 63, q = lane >> 4, ln = lane & 15;

    if (bx < 112) {
        // ---------------- gconv branch ----------------
        int hx = bx >> 2, g = bx & 3;
        int h0 = hx * 2;
        bf16* As = SH;
        #pragma unroll
        for (int i = 0; i < 8; i++) {
            int slot = t + i * 256;
            if (slot < 1856) {
                int pos = slot >> 3, chunkL = slot & 7;
                int ri = pos / 58, ci = pos - ri * 58;
                int chunkg = chunkL ^ (pos & 7);
                float4 v = *(const float4*)(xp + (((long)b * PPIX + (h0 + ri) * 58 + ci) * 256 + g * 64 + chunkg * 8));
                *(float4*)&SH[pos * 64 + chunkL * 8] = v;
            }
        }
        int posb[7];
        #pragma unroll
        for (int pt = 0; pt < 7; pt++) {
            int p = pt * 16 + ln;
            int prow = (p >= 56) ? 1 : 0;
            int pcol = p - prow * 56;
            posb[pt] = prow * 58 + pcol + 1;
        }
        const bf16* wbase = wT + ((long)(g * 9) * 64 + wv * 16 + ln) * 64;
        __syncthreads();

        f32x4 acc[7] = {};
        #pragma unroll
        for (int tap = 0; tap < 9; tap++) {
            const int dr = tap / 3;
            const int dc = tap % 3 - 1;
            const bf16* wq = wbase + tap * 64 * 64;
            s16x8 B0 = *(const s16x8*)(wq + q * 8);
            s16x8 B1 = *(const s16x8*)(wq + 32 + q * 8);
            #pragma unroll
            for (int pt = 0; pt < 7; pt++) {
                int pos = posb[pt] + dr * 58 + dc;
                int off0 = pos * 64 + ((q ^ (pos & 7)) * 8);
                s16x8 a0 = *(const s16x8*)&As[off0];
                s16x8 a1 = *(const s16x8*)&As[off0 ^ 32];
                acc[pt] = __builtin_amdgcn_mfma_f32_16x16x32_bf16(a0, B0, acc[pt], 0, 0, 0);
                acc[pt] = __builtin_amdgcn_mfma_f32_16x16x32_bf16(a1, B1, acc[pt], 0, 0, 0);
            }
        }
        __syncthreads();
        bf16* T = As;                      // 112 x 72
        int co = g * 64 + wv * 16 + ln;
        float sc = kes[co], bi = keb[co];
        #pragma unroll
        for (int pt = 0; pt < 7; pt++)
            #pragma unroll
            for (int r = 0; r < 4; r++)
                T[(pt * 16 + q * 4 + r) * 72 + wv * 16 + ln] = f2b(fmaxf(acc[pt][r] * sc + bi, 0.f));
        __syncthreads();
        int pimg0 = hx * 112;
        #pragma unroll
        for (int i = 0; i < 4; i++) {
            int slot = t + i * 256;
            if (slot < 896) {
                int row = slot >> 3, cc = slot & 7;
                *(float4*)(kh + ((long)b * NPIX + pimg0 + row) * CDIM + g * 64 + cc * 8) = *(const float4*)&T[row * 72 + cc * 8];
            }
        }
        {
            int co_l = t & 63, rb = t >> 6;
            float s = 0.f;
            #pragma unroll
            for (int r = 0; r < 28; r++) s += b2f(T[(rb * 28 + r) * 72 + co_l]);
            atomicAdd(&gap[b * 256 + g * 64 + co_l], s);
        }
    } else {
        // ---------------- c1 branch (K=256, M=256, padded out) ----------------
        int px = bx - 112;
        int mt = px & 1; px >>= 1;         // px in [0,49)
        int p0 = px * 64;
        int m0 = mt * 128;
        bf16* As = SH;                     // 64 x 72
        bf16* Bs = SH + 64 * 72;           // 128 x 72

        f32x4 acc[4][2] = {};
        for (int k0 = 0; k0 < 256; k0 += 64) {
            __syncthreads();
            #pragma unroll
            for (int i = 0; i < 2; i++) {
                int slot = t + i * 256;
                int chunk = slot & 7, row = slot >> 3;
                long pp = p0 + row;
                long pidx = (long)b * PPIX + pp + 2 * (pp / HDIM) + 59;
                *(float4*)&As[row * 72 + chunk * 8] = *(const float4*)(xp + pidx * 256 + k0 + chunk * 8);
            }
            #pragma unroll
            for (int i = 0; i < 4; i++) {
                int slot = t + i * 256;
                int chunk = slot & 7, row = slot >> 3;
                *(float4*)&Bs[row * 72 + chunk * 8] = *(const float4*)(c1w + (long)(m0 + row) * 256 + k0 + chunk * 8);
            }
            __syncthreads();
            #pragma unroll
            for (int kk = 0; kk < 2; kk++) {
                s16x8 a[4];
                #pragma unroll
                for (int pt = 0; pt < 4; pt++)
                    a[pt] = *(const s16x8*)&As[(pt * 16 + ln) * 72 + kk * 32 + q * 8];
                #pragma unroll
                for (int mi = 0; mi < 2; mi++) {
                    s16x8 bb = *(const s16x8*)&Bs[(wv * 32 + mi * 16 + ln) * 72 + kk * 32 + q * 8];
                    #pragma unroll
                    for (int pt = 0; pt < 4; pt++)
                        acc[pt][mi] = __builtin_amdgcn_mfma_f32_16x16x32_bf16(a[pt], bb, acc[pt][mi], 0, 0, 0);
                }
            }
        }
        __syncthreads();
        bf16* T = SH;                      // 64 x 144
        #pragma unroll
        for (int mi = 0; mi < 2; mi++) {
            int m = m0 + wv * 32 + mi * 16 + ln;
            float sc = c1s[m], bi = c1b[m];
            #pragma unroll
            for (int pt = 0; pt < 4; pt++) {
                #pragma unroll
                for (int r = 0; r < 4; r++) {
                    float v = acc[pt][mi][r] * sc + bi;
                    T[(pt * 16 + q * 4 + r) * 144 + wv * 32 + mi * 16 + ln] = f2b(v);
                }
            }
        }
        __syncthreads();
        #pragma unroll
        for (int i = 0; i < 4; i++) {
            int slot = t + i * 256;
            int row = slot >> 4, chunk = slot & 15;
            long pp = p0 + row;
            long pidx = (long)b * PPIX + pp + 2 * (pp / HDIM) + 59;
            *(float4*)(xq + pidx * 256 + m0 + chunk * 8) = *(const float4*)&T[row * 144 + chunk * 8];
        }
    }
}

// ================= FUSED e1 -> e2 GEMM chain (per-pixel 1x1 convs) =============
// grid (49, 16), block 256. Phase 1: e1 (K=512 from xh|kh, M=128, BN+ReLU) ->
// LDS tile W1[64px][128ch]. Phase 2: e2 (K=128 from W1, M=288, +bias) -> wemb,
// with fused GN partial sums. Eliminates the w1 global round-trip.
__global__ __launch_bounds__(256) void mfma_e12(
    const bf16* __restrict__ e1w, const bf16* __restrict__ e2w,
    const bf16* __restrict__ X0, const bf16* __restrict__ X1,
    const float* __restrict__ e1s, const float* __restrict__ e1b,
    const float* __restrict__ e2bias,
    bf16* __restrict__ Y, float* __restrict__ gnsum)
{
    int b = blockIdx.y;
    int p0 = blockIdx.x * 64;
    __shared__ bf16 SH[17920];        // ph1: As(4608)|Bs(9216); ph2: W1(8704)|Bs2/T(9216)
    __shared__ float gs[64];
    int t = threadIdx.x;
    int wv = t >> 6, lane = t & 63, q = lane >> 4, ln = lane & 15;
    if (t < 64) gs[t] = 0.f;

    // ---------------- phase 1: e1 ----------------
    {
        bf16* As = SH;
        bf16* Bs = SH + 4608;
        f32x4 acc[4][2] = {};
        for (int k0 = 0; k0 < 512; k0 += 64) {
            __syncthreads();
            #pragma unroll
            for (int i = 0; i < 2; i++) {
                int slot = t + i * 256;
                int chunk = slot & 7, row = slot >> 3;
                int ch = k0 + chunk * 8;
                const bf16* src;
                if (ch < 256) {
                    long pp = p0 + row;
                    long pidx = (long)b * PPIX + pp + 2 * (pp / HDIM) + 59;
                    src = X0 + pidx * 256 + ch;
                } else {
                    src = X1 + ((long)b * NPIX + p0 + row) * 256 + (ch - 256);
                }
                *(float4*)&As[row * 72 + chunk * 8] = *(const float4*)src;
            }
            #pragma unroll
            for (int i = 0; i < 4; i++) {
                int slot = t + i * 256;
                int chunk = slot & 7, row = slot >> 3;
                *(float4*)&Bs[row * 72 + chunk * 8] = *(const float4*)(e1w + (long)row * 512 + k0 + chunk * 8);
            }
            __syncthreads();
            #pragma unroll
            for (int kk = 0; kk < 2; kk++) {
                s16x8 a[4];
                #pragma unroll
                for (int pt = 0; pt < 4; pt++)
                    a[pt] = *(const s16x8*)&As[(pt * 16 + ln) * 72 + kk * 32 + q * 8];
                #pragma unroll
                for (int mi = 0; mi < 2; mi++) {
                    s16x8 bb = *(const s16x8*)&Bs[(wv * 32 + mi * 16 + ln) * 72 + kk * 32 + q * 8];
                    #pragma unroll
                    for (int pt = 0; pt < 4; pt++)
                        acc[pt][mi] = __builtin_amdgcn_mfma_f32_16x16x32_bf16(a[pt], bb, acc[pt][mi], 0, 0, 0);
                }
            }
        }
        __syncthreads();                   // As/Bs dead; write W1
        bf16* W1 = SH;                     // 64 x 136 (stride 136, 8704 elems)
        #pragma unroll
        for (int mi = 0; mi < 2; mi++) {
            int m = wv * 32 + mi * 16 + ln;
            float sc = e1s[m], bi = e1b[m];
            #pragma unroll
            for (int pt = 0; pt < 4; pt++) {
                #pragma unroll
                for (int r = 0; r < 4; r++) {
                    float v = fmaxf(acc[pt][mi][r] * sc + bi, 0.f);
                    W1[(pt * 16 + q * 4 + r) * 136 + m] = f2b(v);
                }
            }
        }
        __syncthreads();
    }

    // ---------------- phase 2: e2 (A = W1 in LDS) ----------------
    {
        bf16* W1 = SH;
        bf16* Bs = SH + 8704;              // 128 x 72 per k-step; T aliases
        for (int mt = 0; mt < 3; mt++) {
            int m0 = mt * 128;
            f32x4 acc[4][2] = {};
            for (int k0 = 0; k0 < 128; k0 += 64) {
                __syncthreads();
                #pragma unroll
                for (int i = 0; i < 4; i++) {
                    int slot = t + i * 256;
                    int chunk = slot & 7, row = slot >> 3;
                    int m = m0 + row;
                    float4 v = {0.f, 0.f, 0.f, 0.f};
                    if (m < 288) v = *(const float4*)(e2w + (long)m * 128 + k0 + chunk * 8);
                    *(float4*)&Bs[row * 72 + chunk * 8] = v;
                }
                __syncthreads();
                #pragma unroll
                for (int kk = 0; kk < 2; kk++) {
                    s16x8 a[4];
                    #pragma unroll
                    for (int pt = 0; pt < 4; pt++)
                        a[pt] = *(const s16x8*)&W1[(pt * 16 + ln) * 136 + k0 + kk * 32 + q * 8];
                    #pragma unroll
                    for (int mi = 0; mi < 2; mi++) {
                        s16x8 bb = *(const s16x8*)&Bs[(wv * 32 + mi * 16 + ln) * 72 + kk * 32 + q * 8];
                        #pragma unroll
                        for (int pt = 0; pt < 4; pt++)
                            acc[pt][mi] = __builtin_amdgcn_mfma_f32_16x16x32_bf16(a[pt], bb, acc[pt][mi], 0, 0, 0);
                    }
                }
            }
            __syncthreads();               // Bs dead -> T
            bf16* T = Bs;                  // 64 x 144 = 9216 elems
            #pragma unroll
            for (int mi = 0; mi < 2; mi++) {
                int m = m0 + wv * 32 + mi * 16 + ln;
                int mc = (m > 287) ? 287 : m;
                float bi = e2bias[mc];
                float ps = 0.f, pq = 0.f;
                #pragma unroll
                for (int pt = 0; pt < 4; pt++) {
                    #pragma unroll
                    for (int r = 0; r < 4; r++) {
                        float v = acc[pt][mi][r] + bi;
                        ps += v; pq += v * v;
                        T[(pt * 16 + q * 4 + r) * 144 + wv * 32 + mi * 16 + ln] = f2b(v);
                    }
                }
                if (m < 288) {
                    int grp = m / 9;
                    atomicAdd(&gs[grp * 2], ps);
                    atomicAdd(&gs[grp * 2 + 1], pq);
                }
            }
            __syncthreads();
            #pragma unroll
            for (int i = 0; i < 4; i++) {
                int slot = t + i * 256;
                int chunk = slot & 15, row = slot >> 4;
                int m = m0 + chunk * 8;
                if (m + 8 <= 288)
                    *(float4*)(Y + ((long)b * NPIX + p0 + row) * 288 + m) = *(const float4*)&T[row * 144 + chunk * 8];
            }
        }
    }
    if (t < 64) atomicAdd(&gnsum[b * 64 + t], gs[t]);
}

// ================= gnfold: GN affine folds, once per (b, grp, tap) =============
__global__ void gnfold(const float* __restrict__ gnsum,
                       const float* __restrict__ gng, const float* __restrict__ gnb,
                       float* __restrict__ o)
{
    int b = blockIdx.x, t = threadIdx.x;
    for (int s = t; s < 288; s += 256) {
        int g2 = s / 9;
        float S = gnsum[b * 64 + g2 * 2], Q = gnsum[b * 64 + g2 * 2 + 1];
        float mu = S * (1.f / 28224.f);
        float var = Q * (1.f / 28224.f) - mu * mu;
        float rs = rsqrtf(fmaxf(var, 0.f) + 1e-5f);
        float a = rs * gng[s];
        o[O_SA + b * 576 + s] = a;
        o[O_SA + b * 576 + 288 + s] = gnb[s] - mu * a;
    }
}

// ================= dynamic local conv + GN(folded) + BN(b2) + swish + y-GAP ====
__global__ __launch_bounds__(256) void dynconv(
    const bf16* __restrict__ xq, const bf16* __restrict__ wemb,
    const float* __restrict__ fold,
    const float* __restrict__ b2s, const float* __restrict__ b2b,
    bf16* __restrict__ y, float* __restrict__ gap)
{
    int t = threadIdx.x;
    int grp = t & 31, pl = t >> 5;
    int bid = blockIdx.x;                  // 16 b x 392 tiles
    int b = bid / 392;
    int p0 = (bid - b * 392) * 8;
    int p = p0 + pl;
    int h = p / HDIM, w = p - h * HDIM;    // all 8 pixels in one row (8 | 56)

    __shared__ bf16 WE[2304];              // 8 px x 288, contiguous slab
    __shared__ float SAB[576];             // SA[0..288) | SC[288..576)
    __shared__ float R[8][256];

    {
        const bf16* src = wemb + (long)(b * NPIX + p0) * 288;
        #pragma unroll
        for (int i = 0; i < 2; i++) {
            int s = t + i * 256;
            if (s < 288) *(float4*)&WE[s * 8] = *(const float4*)(src + s * 8);
        }
    }
    {
        const float4* src = (const float4*)(fold + O_SA + b * 576);
        if (t < 144) ((float4*)SAB)[t] = src[t];
    }
    __syncthreads();

    // ---- 9 unconditional tap loads from padded xq ----
    long base = ((long)b * PPIX + (h + 1) * 58 + (w + 1)) * 256 + grp * 8;
    const bf16* rm = xq + base - 58 * 256;
    const bf16* rc = xq + base;
    const bf16* rq = xq + base + 58 * 256;
    s16x8 xv[9];
    xv[0] = *(const s16x8*)(rm - 256); xv[1] = *(const s16x8*)rm; xv[2] = *(const s16x8*)(rm + 256);
    xv[3] = *(const s16x8*)(rc - 256); xv[4] = *(const s16x8*)rc; xv[5] = *(const s16x8*)(rc + 256);
    xv[6] = *(const s16x8*)(rq - 256); xv[7] = *(const s16x8*)rq; xv[8] = *(const s16x8*)(rq + 256);

    float acc[8] = {};
    #pragma unroll
    for (int tp = 0; tp < 9; tp++) {
        int wi = grp * 9 + tp;
        float wt = b2f(WE[pl * 288 + wi]) * SAB[wi] + SAB[288 + wi];
        const bf16* xb = (const bf16*)&xv[tp];
        #pragma unroll
        for (int i = 0; i < 8; i++) acc[i] += b2f(xb[i]) * wt;
    }

    bf16 outv[8];
    float sv[8];
    #pragma unroll
    for (int i = 0; i < 8; i++) {
        int c = grp * 8 + i;
        float v = acc[i] * b2s[c] + b2b[c];
        float sw = v / (1.f + __expf(-v));
        sv[i] = sw;
        outv[i] = f2b(sw);
    }
    *(float4*)(y + ((long)b * NPIX + p) * CDIM + grp * 8) = *(const float4*)outv;

    // ---- fused y-GAP: reduce 8 pixels per block in LDS, 1 atomic/thread ----
    #pragma unroll
    for (int i = 0; i < 8; i++) R[pl][grp * 8 + i] = sv[i];
    __syncthreads();
    float s = 0.f;
    #pragma unroll
    for (int j = 0; j < 8; j++) s += R[j][t];
    atomicAdd(&gap[b * 256 + t], s);
}

// ================= split attention ============================================
__global__ void attnk(const float* __restrict__ gap,
                      const float* __restrict__ s1w, const float* __restrict__ s1b,
                      const float* __restrict__ s1s, const float* __restrict__ s1bi,
                      const float* __restrict__ s2w, const float* __restrict__ s2b,
                      float* __restrict__ att)
{
    int b = blockIdx.x, t = threadIdx.x;   // 128 threads
    __shared__ float g[256], a1[128];
    for (int i = t; i < 256; i += 128) g[i] = gap[b * 256 + i] * (1.f / NPIX);
    __syncthreads();
    float s = 0.f;
    for (int ci = 0; ci < 256; ci++) s += s1w[t * 256 + ci] * g[ci];
    s += s1b[t];
    s = s * s1s[t] + s1bi[t];
    a1[t] = fmaxf(s, 0.f);
    __syncthreads();
    for (int c = t; c < 256; c += 128) {
        float v0 = s2b[2 * c], v1 = s2b[2 * c + 1];
        for (int ci = 0; ci < 128; ci++) {
            float av = a1[ci];
            v0 += s2w[(2 * c) * 128 + ci] * av;
            v1 += s2w[(2 * c + 1) * 128 + ci] * av;
        }
        float m = fmaxf(v0, v1);
        float e0 = __expf(v0 - m), e1 = __expf(v1 - m);
        float inv = 1.f / (e0 + e1);
        att[(b * 256 + c) * 2 + 0] = e0 * inv;
        att[(b * 256 + c) * 2 + 1] = e1 * inv;
    }
}

// ================= final: combine + NHWC->NCHW fp32 out =======================
__global__ __launch_bounds__(256) void finalk(
    const bf16* __restrict__ y, const bf16* __restrict__ k,
    const float* __restrict__ att, float* __restrict__ out)
{
    int b = blockIdx.z, c0 = blockIdx.y * 64, p0 = blockIdx.x * 64;
    __shared__ bf16 Ys[64][72], Ks[64][72];
    int t = threadIdx.x;
    #pragma unroll
    for (int i = 0; i < 2; i++) {
        int slot = t + i * 256;
        int row = slot >> 3, cc = slot & 7;
        long off = ((long)b * NPIX + p0 + row) * CDIM + c0 + cc * 8;
        *(float4*)&Ys[row][cc * 8] = *(const float4*)(y + off);
        *(float4*)&Ks[row][cc * 8] = *(const float4*)(k + off);
    }
    __syncthreads();
    int c_l = t >> 2, pc = t & 3;
    int c = c0 + c_l;
    float a0 = att[(b * 256 + c) * 2], a1 = att[(b * 256 + c) * 2 + 1];
    float4 o[4];
    float* of = (float*)o;
    #pragma unroll
    for (int j = 0; j < 16; j++) {
        int p = pc * 16 + j;
        of[j] = b2f(Ys[p][c_l]) * a0 + b2f(Ks[p][c_l]) * a1;
    }
    float* dst = out + ((long)b * CDIM + c) * NPIX + p0 + pc * 16;
    #pragma unroll
    for (int j = 0; j < 4; j++) ((float4*)dst)[j] = o[j];
}

extern "C" void kernel_launch(void* const* d_in, const int* in_sizes, int n_in,
                              void* d_out, int out_size, void* d_ws, size_t ws_size,
                              hipStream_t stream)
{
    const float* x    = (const float*)d_in[0];
    const float* ke_w = (const float*)d_in[1];
    const float* ke_g = (const float*)d_in[2];
    const float* ke_b = (const float*)d_in[3];
    const float* ke_m = (const float*)d_in[4];
    const float* ke_v = (const float*)d_in[5];
    const float* e1_w = (const float*)d_in[6];
    const float* e1_g = (const float*)d_in[7];
    const float* e1_b = (const float*)d_in[8];
    const float* e1_m = (const float*)d_in[9];
    const float* e1_v = (const float*)d_in[10];
    const float* e2_w = (const float*)d_in[11];
    const float* e2_b = (const float*)d_in[12];
    const float* gng  = (const float*)d_in[13];
    const float* gnb  = (const float*)d_in[14];
    const float* c1_w = (const float*)d_in[15];
    const float* c1_g = (const float*)d_in[16];
    const float* c1_b = (const float*)d_in[17];
    const float* c1_m = (const float*)d_in[18];
    const float* c1_v = (const float*)d_in[19];
    const float* b2_g = (const float*)d_in[20];
    const float* b2_b = (const float*)d_in[21];
    const float* b2_m = (const float*)d_in[22];
    const float* b2_v = (const float*)d_in[23];
    const float* s1_w = (const float*)d_in[24];
    const float* s1_b = (const float*)d_in[25];
    const float* s1_g = (const float*)d_in[26];
    const float* s1_bb= (const float*)d_in[27];
    const float* s1_m = (const float*)d_in[28];
    const float* s1_v = (const float*)d_in[29];
    const float* s2_w = (const float*)d_in[30];
    const float* s2_b = (const float*)d_in[31];

    float* fold = (float*)d_ws;           // 128 KB
    bf16* wsb   = (bf16*)((char*)d_ws + 131072);
    bf16* xh   = wsb;                     // padded: 16*3364*256 = 13,778,944
    bf16* kh   = xh + 13778944L;          // 12,845,056
    bf16* wemb = kh + 12845056L;          // 14,450,688
    bf16* kewT = wemb + 14450688L;        // 147,456
    bf16* e1wb = kewT + 147456L;          // 65,536
    bf16* e2wb = e1wb + 65536L;           // 36,864
    bf16* c1wb = e2wb + 36864L;           // 65,536
    bf16* xq   = c1wb + 65536L;           // padded: 13,778,944
    bf16* yb   = xh;                      // alias (xh dead after e12; unpadded)

    preconv<<<dim3(5301), dim3(256), 0, stream>>>(
        x, ke_w, e1_w, e2_w, c1_w,
        ke_g, ke_b, ke_m, ke_v, e1_g, e1_b, e1_m, e1_v, e2_b,
        c1_g, c1_b, c1_m, c1_v, b2_g, b2_b, b2_m, b2_v,
        s1_g, s1_bb, s1_m, s1_v,
        kewT, e1wb, e2wb, c1wb, fold, xh, xq);

    gconv_c1<<<dim3(210, 1, 16), dim3(256), 0, stream>>>(
        xh, kewT, fold + O_KE_S, fold + O_KE_B,
        c1wb, fold + O_C1_S, fold + O_C1_B,
        kh, xq, fold + O_GAP);

    mfma_e12<<<dim3(49, 16), dim3(256), 0, stream>>>(
        e1wb, e2wb, xh, kh, fold + O_E1_S, fold + O_E1_B, fold + O_E2B,
        wemb, fold + O_GNS);

    gnfold<<<dim3(16), dim3(256), 0, stream>>>(fold + O_GNS, gng, gnb, fold);

    dynconv<<<dim3(6272), dim3(256), 0, stream>>>(
        xq, wemb, fold, fold + O_B2_S, fold + O_B2_B, yb, fold + O_GAP);

    attnk<<<dim3(16), dim3(128), 0, stream>>>(
        fold + O_GAP, s1_w, s1_b, fold + O_S1_S, fold + O_S1_B, s2_w, s2_b, fold + O_ATT);

    finalk<<<dim3(49, 4, 16), dim3(256), 0, stream>>>(yb, kh, fold + O_ATT, (float*)d_out);
}